// Round 9
// baseline (1394.662 us; speedup 1.0000x reference)
//
#include <hip/hip_runtime.h>
#include <hip/hip_bf16.h>

#define B_ 32
#define DIM_ 384
#define R_ 28
#define N_ 784
#define H_ 8
#define KD_ 32
#define D_ 128
#define DH_ 1024
#define PSTR_ 832
#define SCALE_ 0.17677669529663687f

typedef unsigned short u16;
typedef __attribute__((ext_vector_type(4))) float f32x4;
typedef __attribute__((ext_vector_type(8))) short s16x8;

__device__ __forceinline__ float b2f(u16 b) {
  union { unsigned int u; float f; } v; v.u = ((unsigned int)b) << 16; return v.f;
}
__device__ __forceinline__ u16 f2b(float f) {
  union { float f; unsigned int u; } v; v.f = f;
  unsigned int r = v.u + 0x7fffu + ((v.u >> 16) & 1u);
  return (u16)(r >> 16);
}
// y = m / 28 for m < 65536 (magic: 2341 = ceil(2^16/28))
__device__ __forceinline__ int div28(int m) { return (m * 2341) >> 16; }
// y = t / 784 for t < 25088 (magic: 5350 = ceil(2^22/784))
__device__ __forceinline__ int div784(int t) { return (int)(((long long)t * 5350) >> 22); }

// async global->LDS 16B copy. LDS dest is wave-uniform base + lane*16 (linear).
__device__ __forceinline__ void gl_lds16(const u16* g, u16* l) {
  __builtin_amdgcn_global_load_lds(
      (const __attribute__((address_space(1))) unsigned int*)g,
      (__attribute__((address_space(3))) unsigned int*)l, 16, 0, 0);
}

// ---------------- weight convert f32 -> bf16 (4 arrays) ----------------
struct CvtTab { const float* src[4]; u16* dst[4]; int n[4]; };

__global__ __launch_bounds__(256) void k_cvt(CvtTab tab) {
  int a = blockIdx.y;
  int n4 = tab.n[a] >> 2;
  const float4* s = (const float4*)tab.src[a];
  ushort4* d = (ushort4*)tab.dst[a];
  for (int i = blockIdx.x * 256 + threadIdx.x; i < n4; i += gridDim.x * 256) {
    float4 v = s[i];
    ushort4 o;
    o.x = f2b(v.x); o.y = f2b(v.y); o.z = f2b(v.z); o.w = f2b(v.w);
    d[i] = o;
  }
}

// ---------------- abmix: abm[idx][g] = sum_h th1w[g,h]*ab[h,idx] + th1b[g] ----------------
__global__ __launch_bounds__(256) void k_abmix(const float* __restrict__ ab,
                                               const float* __restrict__ th1w,
                                               const float* __restrict__ th1b,
                                               float* __restrict__ abm) {
  int t = blockIdx.x * 256 + threadIdx.x;
  if (t >= 8 * N_) return;
  int i = t >> 3, g = t & 7;
  float s = th1b[g];
  for (int h = 0; h < 8; ++h) s += th1w[g * 8 + h] * ab[h * N_ + i];
  abm[i * 8 + g] = s;
}

// ---------------- K0: transpose x(f32) [b][c][n] -> xT(bf16) [bl][n][c] ----------------
__global__ __launch_bounds__(256) void k_transpose(const float* __restrict__ x,
                                                   u16* __restrict__ xT, int b0) {
  __shared__ u16 tile[64][65];
  int nt = blockIdx.x, ct = blockIdx.y, bl = blockIdx.z;
  int t = threadIdx.x;
  int n0 = nt * 64, c0 = ct * 64;
  const float* xb = x + (size_t)(b0 + bl) * DIM_ * N_;
  int nl = t & 63, cg = t >> 6;
  for (int i = 0; i < 16; ++i) {
    int cl = cg * 16 + i;
    int n = n0 + nl;
    u16 val = 0;
    if (n < N_) val = f2b(xb[(size_t)(c0 + cl) * N_ + n]);
    tile[cl][nl] = val;
  }
  __syncthreads();
  u16* xTb = xT + (size_t)bl * N_ * DIM_;
  int cl = t & 63, ng = t >> 6;
  for (int i = 0; i < 16; ++i) {
    int n2 = n0 + ng * 16 + i;
    if (n2 < N_) xTb[(size_t)n2 * DIM_ + (c0 + cl)] = tile[cl][ng * 16 + i];
  }
}

// ---------------- K1: QKV projection, staged 128x128 tile, BK=64, XOR-swizzled LDS --------
// A = weights (rows oc), B = xT tokens (rows tg over all G batches).
__global__ __launch_bounds__(256) void k_proj(
    const u16* __restrict__ xT,
    const u16* __restrict__ wqb, const u16* __restrict__ wkb, const u16* __restrict__ wvb,
    const float* __restrict__ bq, const float* __restrict__ sq, const float* __restrict__ tq,
    const float* __restrict__ bk, const float* __restrict__ sk, const float* __restrict__ tk,
    const float* __restrict__ bv, const float* __restrict__ sv, const float* __restrict__ tv,
    u16* __restrict__ qb, u16* __restrict__ kb, u16* __restrict__ vb, int ntok) {
  __shared__ u16 ldsA[128 * 64];
  __shared__ u16 ldsB[128 * 64];
  int nt = blockIdx.x, mt = blockIdx.y;
  int t = threadIdx.x;
  int oc0 = mt * 128;
  const u16* Wsrc; const float *bsrc, *ssrc, *tsrc; int obase;
  if (mt < 2)      { Wsrc = wqb; bsrc = bq; ssrc = sq; tsrc = tq; obase = oc0; }
  else if (mt < 4) { Wsrc = wkb; bsrc = bk; ssrc = sk; tsrc = tk; obase = oc0 - 256; }
  else             { Wsrc = wvb; bsrc = bv; ssrc = sv; tsrc = tv; obase = oc0 - 512; }

  int lane = t & 63, wid = t >> 6;
  int wm = wid & 1, wn = wid >> 1;
  int l16 = lane & 15, quad = lane >> 4;

  f32x4 acc[4][4] = {};
  for (int kc = 0; kc < DIM_ / 64; ++kc) {
    __syncthreads();
    #pragma unroll
    for (int j = 0; j < 4; ++j) {
      int s = j * 256 + t;
      int row = s >> 3, ch = s & 7;
      int gc = (ch ^ (row & 7)) * 8;
      gl_lds16(Wsrc + (size_t)(obase + row) * DIM_ + kc * 64 + gc, ldsA + s * 8);
    }
    #pragma unroll
    for (int j = 0; j < 4; ++j) {
      int s = j * 256 + t;
      int row = s >> 3, ch = s & 7;
      int gc = (ch ^ (row & 7)) * 8;
      int tr = nt * 128 + row; if (tr >= ntok) tr = ntok - 1;
      gl_lds16(xT + (size_t)tr * DIM_ + kc * 64 + gc, ldsB + s * 8);
    }
    __syncthreads();
    #pragma unroll
    for (int kc2 = 0; kc2 < 2; ++kc2) {
      s16x8 a[4], b[4];
      #pragma unroll
      for (int mi = 0; mi < 4; ++mi) {
        int row = wm * 64 + mi * 16 + l16;
        int ch = (kc2 * 4 + quad) ^ (l16 & 7);
        a[mi] = *(const s16x8*)&ldsA[row * 64 + ch * 8];
      }
      #pragma unroll
      for (int ni = 0; ni < 4; ++ni) {
        int row = wn * 64 + ni * 16 + l16;
        int ch = (kc2 * 4 + quad) ^ (l16 & 7);
        b[ni] = *(const s16x8*)&ldsB[row * 64 + ch * 8];
      }
      #pragma unroll
      for (int mi = 0; mi < 4; ++mi)
        #pragma unroll
        for (int ni = 0; ni < 4; ++ni)
          acc[mi][ni] = __builtin_amdgcn_mfma_f32_16x16x32_bf16(a[mi], b[ni], acc[mi][ni], 0, 0, 0);
    }
  }
  for (int mi = 0; mi < 4; ++mi)
    for (int ni = 0; ni < 4; ++ni) {
      int row0 = wm * 64 + mi * 16 + quad * 4;
      int tg = nt * 128 + wn * 64 + ni * 16 + l16;
      if (tg >= ntok) continue;
      int bl = div784(tg);
      int col = tg - bl * N_;
      int ol0 = obase + row0;
      float4 bb = *(const float4*)&bsrc[ol0];
      float4 ss = *(const float4*)&ssrc[ol0];
      float4 tt = *(const float4*)&tsrc[ol0];
      float v0 = (acc[mi][ni][0] + bb.x) * ss.x + tt.x;
      float v1 = (acc[mi][ni][1] + bb.y) * ss.y + tt.y;
      float v2 = (acc[mi][ni][2] + bb.z) * ss.z + tt.z;
      float v3 = (acc[mi][ni][3] + bb.w) * ss.w + tt.w;
      int oc = oc0 + row0;
      if (oc < 512) {
        int h = (oc & 255) >> 5, c0 = oc & 31;
        u16* dst = (oc < 256) ? qb : kb;
        ushort4 o;
        o.x = f2b(v0); o.y = f2b(v1); o.z = f2b(v2); o.w = f2b(v3);
        *(ushort4*)&dst[(((size_t)bl * H_ + h) * N_ + col) * KD_ + c0] = o;
      } else {
        int ch = oc - 512;
        vb[((size_t)bl * DH_ + ch) * N_ + col] = f2b(v0);
        vb[((size_t)bl * DH_ + ch + 1) * N_ + col] = f2b(v1);
        vb[((size_t)bl * DH_ + ch + 2) * N_ + col] = f2b(v2);
        vb[((size_t)bl * DH_ + ch + 3) * N_ + col] = f2b(v3);
      }
    }
}

// ---------------- K2: depthwise 3x3 conv + affine; wave-per-channel ----------------
__global__ __launch_bounds__(256) void k_dwconv(
    const u16* __restrict__ vb, const float* __restrict__ Wvl,
    const float* __restrict__ bvl, const float* __restrict__ svl, const float* __restrict__ tvl,
    u16* __restrict__ vlb) {
  __shared__ u16 img[4][N_];
  int cg = blockIdx.x, bl = blockIdx.y;
  int t = threadIdx.x;
  int wid = t >> 6, lane = t & 63;
  int ch = cg * 4 + wid;
  const u16* vp = vb + ((size_t)bl * DH_ + ch) * N_;
  for (int i = lane; i < N_; i += 64) img[wid][i] = vp[i];
  __syncthreads();
  float w[9];
  for (int i = 0; i < 9; ++i) w[i] = Wvl[ch * 9 + i];
  float bias = bvl[ch], sc = svl[ch], sh = tvl[ch];
  u16* op = vlb + ((size_t)bl * DH_ + ch) * N_;
  for (int p = lane; p < N_; p += 64) {
    int y = p / R_, x = p - y * R_;
    float acc = 0.f;
    #pragma unroll
    for (int dy = -1; dy <= 1; ++dy) {
      int yy = y + dy;
      if (yy < 0 || yy >= R_) continue;
      #pragma unroll
      for (int dx = -1; dx <= 1; ++dx) {
        int xx = x + dx;
        if (xx < 0 || xx >= R_) continue;
        acc += b2f(img[wid][yy * R_ + xx]) * w[(dy + 1) * 3 + (dx + 1)];
      }
    }
    op[p] = f2b((acc + bias) * sc + sh);
  }
}

// ---------------- K3a: pass 1 of fused attention, m-split across blocks ----------------
// Grid (49 ntile, 4 msplit, G). Writes partial L to Lbuf[mo][bl][g][n] (unique writer).
// r8: mix1 as f32x4 vector expressions -> v_pk_fma_f32 (2 FMA/issue), halves mix VALU.
__global__ __launch_bounds__(256) void k_attn1(
    const u16* __restrict__ qb, const u16* __restrict__ kb,
    const float* __restrict__ abm, const float* __restrict__ th1w,
    float* __restrict__ Lbuf) {
  __shared__ float abms[N_ * 8];
  __shared__ float w1Ts[64];
  __shared__ float lred[4][8][16];
  int nt = blockIdx.x, mo = blockIdx.y, bl = blockIdx.z;
  int G = gridDim.z;
  int t = threadIdx.x;
  for (int i = t; i < N_ * 8; i += 256) abms[i] = abm[i];
  if (t < 64) w1Ts[(t & 7) * 8 + (t >> 3)] = th1w[t];
  __syncthreads();

  int lane = t & 63, wid = t >> 6;
  int l16 = lane & 15, quad = lane >> 4;
  int koff = quad * 8;
  int n_g = nt * 16 + l16;             // < 784 always (49*16=784)
  int yn = div28(n_g), xn = n_g - yn * R_;
  size_t blb = (size_t)bl * H_ * N_;

  s16x8 qf[8];
  #pragma unroll
  for (int h = 0; h < 8; ++h)
    qf[h] = *(const s16x8*)&qb[(blb + (size_t)h * N_ + n_g) * KD_ + koff];

  float Lp[8] = {};
  #pragma unroll 1
  for (int s = mo; s < 13; s += 4) {
    int mb = s * 64 + wid * 16;
    if (mb >= N_) continue;           // wave-uniform
    f32x4 sm8[8] = {};
    #pragma unroll
    for (int h = 0; h < 8; ++h) {
      s16x8 af = *(const s16x8*)&kb[(blb + (size_t)h * N_ + mb + l16) * KD_ + koff];
      f32x4 acc = {};
      acc = __builtin_amdgcn_mfma_f32_16x16x32_bf16(af, qf[h], acc, 0, 0, 0);
      f32x4 wA = *(const f32x4*)&w1Ts[h * 8];
      f32x4 wB = *(const f32x4*)&w1Ts[h * 8 + 4];
      #pragma unroll
      for (int g = 0; g < 4; ++g) {
        sm8[g]     += acc * wA[g];
        sm8[g + 4] += acc * wB[g];
      }
    }
    int mc = mb + quad * 4;
    #pragma unroll
    for (int r = 0; r < 4; ++r) {
      int m = mc + r;
      int ym = div28(m), xm = m - ym * R_;
      int dy = yn - ym; dy = dy < 0 ? -dy : dy;
      int dx = xn - xm; dx = dx < 0 ? -dx : dx;
      int idx = (dy * R_ + dx) * 8;
      f32x4 a0 = *(const f32x4*)&abms[idx];
      f32x4 a1 = *(const f32x4*)&abms[idx + 4];
      #pragma unroll
      for (int g = 0; g < 4; ++g) {
        Lp[g] += __expf(fmaf(sm8[g][r], SCALE_, a0[g]));
        Lp[g + 4] += __expf(fmaf(sm8[g + 4][r], SCALE_, a1[g]));
      }
    }
  }
  #pragma unroll
  for (int g = 0; g < 8; ++g) {
    Lp[g] += __shfl_xor(Lp[g], 16);
    Lp[g] += __shfl_xor(Lp[g], 32);
  }
  if (quad == 0)
    #pragma unroll
    for (int g = 0; g < 8; ++g) lred[wid][g][l16] = Lp[g];
  __syncthreads();
  if (t < 128) {
    int g = t >> 4, nn = t & 15;
    float L = lred[0][g][nn] + lred[1][g][nn] + lred[2][g][nn] + lred[3][g][nn];
    Lbuf[(((size_t)mo * G + bl) * 8 + g) * N_ + nt * 16 + nn] = L;
  }
}

// ---------------- K3b: pass 2 — recompute scores, P = th2-mix(exp*li), m-split ----------
// Grid (cn16, 4 msplit, G). P stride PSTR_; pad [784,832) zero-filled by mo==0 blocks.
// r7 post-mortem: mix2 f-loop must NOT unroll (unrolled: 8x hoisted LDS reads + accs
// -> +~96 live VGPRs -> 256 total -> scratch spill). unroll 1 keeps ~16 transients.
// r8: mix1/mix2 as f32x4 vector expressions -> v_pk_fma_f32 packed math.
__global__ __launch_bounds__(256) void k_attn2(
    const u16* __restrict__ qb, const u16* __restrict__ kb,
    const float* __restrict__ abm, const float* __restrict__ th1w,
    const float* __restrict__ th2w, const float* __restrict__ th2b,
    const float* __restrict__ Lbuf, u16* __restrict__ P, int n0, int NC) {
  __shared__ float abms[N_ * 8];
  __shared__ float w1Ts[64];
  __shared__ float w2s[64];
  __shared__ float b2s[8];
  int nt = blockIdx.x, mo = blockIdx.y, bl = blockIdx.z;
  int G = gridDim.z;
  int t = threadIdx.x;
  for (int i = t; i < N_ * 8; i += 256) abms[i] = abm[i];
  if (t < 64) { w1Ts[(t & 7) * 8 + (t >> 3)] = th1w[t]; w2s[t] = th2w[t]; }
  if (t < 8) b2s[t] = th2b[t];

  if (mo == 0) {
    // zero-fill the m-pad [784, 832) of this block's 16 n-rows, all 8 f
    for (int i = t; i < 8 * 16 * 12; i += 256) {
      int f = i / (16 * 12); int rem = i - f * 16 * 12;
      int nn = rem / 12; int j4 = rem - nn * 12;
      int n_l = nt * 16 + nn;
      if (n_l < NC && (n0 + n_l) < N_) {
        ushort4 z4 = {0, 0, 0, 0};
        *(ushort4*)&P[(((size_t)bl * H_ + f) * NC + n_l) * PSTR_ + 784 + j4 * 4] = z4;
      }
    }
  }
  __syncthreads();

  int lane = t & 63, wid = t >> 6;
  int l16 = lane & 15, quad = lane >> 4;
  int koff = quad * 8;

  int n_loc = nt * 16 + l16;
  int n_g = n0 + n_loc;
  bool nvalid = (n_loc < NC) && (n_g < N_);
  int nq = nvalid ? n_g : N_ - 1;
  int yn = div28(nq), xn = nq - yn * R_;

  size_t blb = (size_t)bl * H_ * N_;

  s16x8 qf[8];
  #pragma unroll
  for (int h = 0; h < 8; ++h)
    qf[h] = *(const s16x8*)&qb[(blb + (size_t)h * N_ + nq) * KD_ + koff];

  float li[8];
  #pragma unroll
  for (int g = 0; g < 8; ++g) {
    float L = 0.f;
    #pragma unroll
    for (int p = 0; p < 4; ++p)
      L += Lbuf[(((size_t)p * G + bl) * 8 + g) * N_ + nq];
    li[g] = 1.f / L;
  }

  #pragma unroll 1
  for (int s = mo; s < 13; s += 4) {
    int mb = s * 64 + wid * 16;
    if (mb >= N_) continue;
    f32x4 sm8[8] = {};
    #pragma unroll
    for (int h = 0; h < 8; ++h) {
      s16x8 af = *(const s16x8*)&kb[(blb + (size_t)h * N_ + mb + l16) * KD_ + koff];
      f32x4 acc = {};
      acc = __builtin_amdgcn_mfma_f32_16x16x32_bf16(af, qf[h], acc, 0, 0, 0);
      f32x4 wA = *(const f32x4*)&w1Ts[h * 8];
      f32x4 wB = *(const f32x4*)&w1Ts[h * 8 + 4];
      #pragma unroll
      for (int g = 0; g < 4; ++g) {
        sm8[g]     += acc * wA[g];
        sm8[g + 4] += acc * wB[g];
      }
    }
    int mc = mb + quad * 4;
    // exp in place: sm8 becomes e*li (no extra register array)
    #pragma unroll
    for (int r = 0; r < 4; ++r) {
      int m = mc + r;
      int ym = div28(m), xm = m - ym * R_;
      int dy = yn - ym; dy = dy < 0 ? -dy : dy;
      int dx = xn - xm; dx = dx < 0 ? -dx : dx;
      int idx = (dy * R_ + dx) * 8;
      f32x4 a0 = *(const f32x4*)&abms[idx];
      f32x4 a1 = *(const f32x4*)&abms[idx + 4];
      #pragma unroll
      for (int g = 0; g < 4; ++g) {
        sm8[g][r] = __expf(fmaf(sm8[g][r], SCALE_, a0[g])) * li[g];
        sm8[g + 4][r] = __expf(fmaf(sm8[g + 4][r], SCALE_, a1[g])) * li[g + 4];
      }
    }
    // streaming mix2: one f at a time; unroll 1 is load-bearing for VGPR budget
    if (nvalid) {
      #pragma unroll 1
      for (int f = 0; f < 8; ++f) {
        f32x4 wA = *(const f32x4*)&w2s[f * 8];
        f32x4 wB = *(const f32x4*)&w2s[f * 8 + 4];
        float b = b2s[f];
        f32x4 o = {b, b, b, b};
        #pragma unroll
        for (int g = 0; g < 4; ++g) {
          o += sm8[g] * wA[g];
          o += sm8[g + 4] * wB[g];
        }
        ushort4 ov;
        ov.x = f2b(o[0]); ov.y = f2b(o[1]);
        ov.z = f2b(o[2]); ov.w = f2b(o[3]);
        *(ushort4*)&P[(((size_t)bl * H_ + f) * NC + n_loc) * PSTR_ + mc] = ov;
      }
    }
  }
}

// ---------------- K5: O' = relu(attn @ V + vl), staged, K=832 (P zero-padded) -------------
// A = V (rows d=128), B = P (rows n, stride PSTR_). acc row=d, col=n.
__global__ __launch_bounds__(256) void k_pv(
    const u16* __restrict__ P, const u16* __restrict__ vb, const u16* __restrict__ vlb,
    u16* __restrict__ ob, int n0, int NC) {
  __shared__ u16 ldsA[128 * 64];
  __shared__ u16 ldsB[128 * 64];
  int ntl = blockIdx.x, z = blockIdx.z;
  int bl = z >> 3, f = z & 7;
  int t = threadIdx.x;
  int lane = t & 63, wid = t >> 6;
  int wm = wid & 1, wn = wid >> 1;
  int l16 = lane & 15, quad = lane >> 4;

  const u16* vsrc = vb + ((size_t)bl * DH_ + f * D_) * N_;
  const u16* asrc = P + ((size_t)bl * H_ + f) * (size_t)NC * PSTR_;

  f32x4 acc[4][4] = {};
  for (int kc = 0; kc < PSTR_ / 64; ++kc) {
    __syncthreads();
    #pragma unroll
    for (int j = 0; j < 4; ++j) {
      int s = j * 256 + t;
      int row = s >> 3, ch = s & 7;
      int gc = (ch ^ (row & 7)) * 8;
      gl_lds16(vsrc + (size_t)row * N_ + kc * 64 + gc, ldsA + s * 8);
    }
    #pragma unroll
    for (int j = 0; j < 4; ++j) {
      int s = j * 256 + t;
      int row = s >> 3, ch = s & 7;
      int gc = (ch ^ (row & 7)) * 8;
      int nr = ntl * 128 + row; if (nr >= NC) nr = NC - 1;
      gl_lds16(asrc + (size_t)nr * PSTR_ + kc * 64 + gc, ldsB + s * 8);
    }
    __syncthreads();
    #pragma unroll
    for (int kc2 = 0; kc2 < 2; ++kc2) {
      s16x8 a[4], b[4];
      #pragma unroll
      for (int mi = 0; mi < 4; ++mi) {
        int row = wm * 64 + mi * 16 + l16;
        int ch = (kc2 * 4 + quad) ^ (l16 & 7);
        a[mi] = *(const s16x8*)&ldsA[row * 64 + ch * 8];
      }
      #pragma unroll
      for (int ni = 0; ni < 4; ++ni) {
        int row = wn * 64 + ni * 16 + l16;
        int ch = (kc2 * 4 + quad) ^ (l16 & 7);
        b[ni] = *(const s16x8*)&ldsB[row * 64 + ch * 8];
      }
      #pragma unroll
      for (int mi = 0; mi < 4; ++mi)
        #pragma unroll
        for (int ni = 0; ni < 4; ++ni)
          acc[mi][ni] = __builtin_amdgcn_mfma_f32_16x16x32_bf16(a[mi], b[ni], acc[mi][ni], 0, 0, 0);
    }
  }
  for (int mi = 0; mi < 4; ++mi)
    for (int ni = 0; ni < 4; ++ni) {
      int row = wm * 64 + mi * 16 + quad * 4;
      int col = wn * 64 + ni * 16 + l16;
      int nloc = ntl * 128 + col;
      if (nloc >= NC || (n0 + nloc) >= N_) continue;
      int ch = f * D_ + row;
      size_t vaddr = ((size_t)bl * DH_ + ch) * N_ + (n0 + nloc);
      float o0 = acc[mi][ni][0] + b2f(vlb[vaddr]);
      float o1 = acc[mi][ni][1] + b2f(vlb[vaddr + N_]);
      float o2 = acc[mi][ni][2] + b2f(vlb[vaddr + 2 * N_]);
      float o3 = acc[mi][ni][3] + b2f(vlb[vaddr + 3 * N_]);
      size_t addr = ((size_t)bl * N_ + (n0 + nloc)) * DH_ + ch;
      ushort4 o4;
      o4.x = f2b(o0 > 0.f ? o0 : 0.f);
      o4.y = f2b(o1 > 0.f ? o1 : 0.f);
      o4.z = f2b(o2 > 0.f ? o2 : 0.f);
      o4.w = f2b(o3 > 0.f ? o3 : 0.f);
      *(ushort4*)&ob[addr] = o4;
    }
}

// ---------------- K6: out = affine(Wp @ O' + bp), staged, f32 out ----------------
__global__ __launch_bounds__(256) void k_outproj(
    const u16* __restrict__ ob, const u16* __restrict__ wpb,
    const float* __restrict__ bp, const float* __restrict__ sp, const float* __restrict__ tp,
    float* __restrict__ out, int b0, int ntok) {
  __shared__ u16 ldsA[128 * 64];
  __shared__ u16 ldsB[128 * 64];
  int nt = blockIdx.x, mt = blockIdx.y;
  int t = threadIdx.x;
  int lane = t & 63, wid = t >> 6;
  int wm = wid & 1, wn = wid >> 1;
  int l16 = lane & 15, quad = lane >> 4;

  f32x4 acc[4][4] = {};
  for (int kc = 0; kc < DH_ / 64; ++kc) {
    __syncthreads();
    #pragma unroll
    for (int j = 0; j < 4; ++j) {
      int s = j * 256 + t;
      int row = s >> 3, ch = s & 7;
      int gc = (ch ^ (row & 7)) * 8;
      gl_lds16(wpb + (size_t)(mt * 128 + row) * DH_ + kc * 64 + gc, ldsA + s * 8);
    }
    #pragma unroll
    for (int j = 0; j < 4; ++j) {
      int s = j * 256 + t;
      int row = s >> 3, ch = s & 7;
      int gc = (ch ^ (row & 7)) * 8;
      int tr = nt * 128 + row; if (tr >= ntok) tr = ntok - 1;
      gl_lds16(ob + (size_t)tr * DH_ + kc * 64 + gc, ldsB + s * 8);
    }
    __syncthreads();
    #pragma unroll
    for (int kc2 = 0; kc2 < 2; ++kc2) {
      s16x8 a[4], b[4];
      #pragma unroll
      for (int mi = 0; mi < 4; ++mi) {
        int row = wm * 64 + mi * 16 + l16;
        int ch = (kc2 * 4 + quad) ^ (l16 & 7);
        a[mi] = *(const s16x8*)&ldsA[row * 64 + ch * 8];
      }
      #pragma unroll
      for (int ni = 0; ni < 4; ++ni) {
        int row = wn * 64 + ni * 16 + l16;
        int ch = (kc2 * 4 + quad) ^ (l16 & 7);
        b[ni] = *(const s16x8*)&ldsB[row * 64 + ch * 8];
      }
      #pragma unroll
      for (int mi = 0; mi < 4; ++mi)
        #pragma unroll
        for (int ni = 0; ni < 4; ++ni)
          acc[mi][ni] = __builtin_amdgcn_mfma_f32_16x16x32_bf16(a[mi], b[ni], acc[mi][ni], 0, 0, 0);
    }
  }
  for (int mi = 0; mi < 4; ++mi)
    for (int ni = 0; ni < 4; ++ni) {
      int row0 = wm * 64 + mi * 16 + quad * 4;
      int tg = nt * 128 + wn * 64 + ni * 16 + l16;
      if (tg >= ntok) continue;
      int bl = div784(tg);
      int n = tg - bl * N_;
      int oc0 = mt * 128 + row0;
      float4 bb = *(const float4*)&bp[oc0];
      float4 ss = *(const float4*)&sp[oc0];
      float4 tt = *(const float4*)&tp[oc0];
      float* o = out + ((size_t)(b0 + bl) * DIM_) * N_ + n;
      o[(size_t)(oc0 + 0) * N_] = (acc[mi][ni][0] + bb.x) * ss.x + tt.x;
      o[(size_t)(oc0 + 1) * N_] = (acc[mi][ni][1] + bb.y) * ss.y + tt.y;
      o[(size_t)(oc0 + 2) * N_] = (acc[mi][ni][2] + bb.z) * ss.z + tt.z;
      o[(size_t)(oc0 + 3) * N_] = (acc[mi][ni][3] + bb.w) * ss.w + tt.w;
    }
}

extern "C" void kernel_launch(void* const* d_in, const int* in_sizes, int n_in,
                              void* d_out, int out_size, void* d_ws, size_t ws_size,
                              hipStream_t stream) {
  (void)in_sizes; (void)n_in; (void)out_size;
  const float* x    = (const float*)d_in[0];
  const float* Wq   = (const float*)d_in[1];
  const float* bq   = (const float*)d_in[2];
  const float* sq   = (const float*)d_in[3];
  const float* tq   = (const float*)d_in[4];
  const float* Wk   = (const float*)d_in[5];
  const float* bk   = (const float*)d_in[6];
  const float* sk   = (const float*)d_in[7];
  const float* tk   = (const float*)d_in[8];
  const float* Wv   = (const float*)d_in[9];
  const float* bv   = (const float*)d_in[10];
  const float* sv   = (const float*)d_in[11];
  const float* tv   = (const float*)d_in[12];
  const float* Wvl  = (const float*)d_in[13];
  const float* bvl  = (const float*)d_in[14];
  const float* svl  = (const float*)d_in[15];
  const float* tvl  = (const float*)d_in[16];
  const float* th1w = (const float*)d_in[17];
  const float* th1b = (const float*)d_in[18];
  const float* th2w = (const float*)d_in[19];
  const float* th2b = (const float*)d_in[20];
  const float* ab   = (const float*)d_in[21];
  const float* Wp   = (const float*)d_in[22];
  const float* bp   = (const float*)d_in[23];
  const float* sp   = (const float*)d_in[24];
  const float* tp   = (const float*)d_in[25];
  float* out = (float*)d_out;

  char* ws = (char*)d_ws;
  size_t off = 0;
  auto alloc = [&](size_t bytes) -> void* {
    void* p = ws + off;
    off += (bytes + 255) & ~(size_t)255;
    return p;
  };

  u16* wqb = (u16*)alloc((size_t)256 * DIM_ * 2);
  u16* wkb = (u16*)alloc((size_t)256 * DIM_ * 2);
  u16* wvb = (u16*)alloc((size_t)DH_ * DIM_ * 2);
  u16* wpb = (u16*)alloc((size_t)DIM_ * DH_ * 2);
  float* abm = (float*)alloc((size_t)N_ * 8 * 4);
  size_t fixed = off;

  auto footprint = [fixed](int G, int NC) -> size_t {
    auto al = [](size_t b) { return (b + 255) & ~(size_t)255; };
    size_t a = fixed;
    a += al((size_t)G * H_ * N_ * KD_ * 2);   // qb
    a += al((size_t)G * H_ * N_ * KD_ * 2);   // kb
    a += al((size_t)G * DH_ * N_ * 2);        // vb
    a += al((size_t)G * DH_ * N_ * 2);        // vlb
    a += al((size_t)G * N_ * DH_ * 2);        // obb
    a += al((size_t)G * N_ * DIM_ * 2);       // xT
    a += al((size_t)4 * G * 8 * N_ * 4);      // Lbuf (4 m-split partials)
    a += al((size_t)G * H_ * NC * PSTR_ * 2); // P (bf16 probs, padded stride)
    return a;
  };
  const int Gs[6] = {32, 16, 8, 4, 2, 1};
  const int NCs[6] = {784, 392, 196, 112, 56, 28};
  int G = 1, NC = 28;
  bool found = false;
  for (int gi = 0; gi < 6 && !found; ++gi)
    for (int ci = 0; ci < 6 && !found; ++ci)
      if (footprint(Gs[gi], NCs[ci]) <= ws_size) { G = Gs[gi]; NC = NCs[ci]; found = true; }

  u16* qb  = (u16*)alloc((size_t)G * H_ * N_ * KD_ * 2);
  u16* kb  = (u16*)alloc((size_t)G * H_ * N_ * KD_ * 2);
  u16* vb  = (u16*)alloc((size_t)G * DH_ * N_ * 2);
  u16* vlb = (u16*)alloc((size_t)G * DH_ * N_ * 2);   // [bl][ch][n]
  u16* obb = (u16*)alloc((size_t)G * N_ * DH_ * 2);
  u16* xT  = (u16*)alloc((size_t)G * N_ * DIM_ * 2);
  float* Lbuf = (float*)alloc((size_t)4 * G * 8 * N_ * 4);
  u16* P   = (u16*)alloc((size_t)G * H_ * NC * PSTR_ * 2);

  CvtTab ct;
  ct.src[0] = Wq; ct.dst[0] = wqb; ct.n[0] = 256 * DIM_;
  ct.src[1] = Wk; ct.dst[1] = wkb; ct.n[1] = 256 * DIM_;
  ct.src[2] = Wv; ct.dst[2] = wvb; ct.n[2] = DH_ * DIM_;
  ct.src[3] = Wp; ct.dst[3] = wpb; ct.n[3] = DIM_ * DH_;
  hipLaunchKernelGGL(k_cvt, dim3(96, 4), dim3(256), 0, stream, ct);
  hipLaunchKernelGGL(k_abmix, dim3(25), dim3(256), 0, stream, ab, th1w, th1b, abm);

  int nchunks = N_ / NC;
  int cn128 = (NC + 127) / 128;
  int cn16 = (NC + 15) / 16;
  int ntok = G * N_;
  int ttiles = (ntok + 127) / 128;
  for (int b0 = 0; b0 < B_; b0 += G) {
    hipLaunchKernelGGL(k_transpose, dim3(13, 6, G), dim3(256), 0, stream, x, xT, b0);
    hipLaunchKernelGGL(k_proj, dim3(ttiles, 12), dim3(256), 0, stream, xT,
                       wqb, wkb, wvb, bq, sq, tq, bk, sk, tk, bv, sv, tv, qb, kb, vb, ntok);
    hipLaunchKernelGGL(k_dwconv, dim3(DH_ / 4, G), dim3(256), 0, stream,
                       vb, Wvl, bvl, svl, tvl, vlb);
    hipLaunchKernelGGL(k_attn1, dim3(49, 4, G), dim3(256), 0, stream,
                       qb, kb, abm, th1w, Lbuf);
    for (int c = 0; c < nchunks; ++c) {
      int n0 = c * NC;
      hipLaunchKernelGGL(k_attn2, dim3(cn16, 4, G), dim3(256), 0, stream,
                         qb, kb, abm, th1w, th2w, th2b, Lbuf, P, n0, NC);
      hipLaunchKernelGGL(k_pv, dim3(cn128, 1, G * H_), dim3(256), 0, stream,
                         P, vb, vlb, obb, n0, NC);
    }
    hipLaunchKernelGGL(k_outproj, dim3(ttiles, 3), dim3(256), 0, stream,
                       obb, wpb, bp, sp, tp, out, b0, ntok);
  }
}

// Round 11
// 877.353 us; speedup vs baseline: 1.5896x; 1.5896x over previous
//
#include <hip/hip_runtime.h>
#include <hip/hip_bf16.h>

#define B_ 32
#define DIM_ 384
#define R_ 28
#define N_ 784
#define H_ 8
#define KD_ 32
#define D_ 128
#define DH_ 1024
#define PSTR_ 832
#define SCALE_ 0.17677669529663687f

typedef unsigned short u16;
typedef __attribute__((ext_vector_type(4))) float f32x4;
typedef __attribute__((ext_vector_type(8))) short s16x8;

__device__ __forceinline__ float b2f(u16 b) {
  union { unsigned int u; float f; } v; v.u = ((unsigned int)b) << 16; return v.f;
}
__device__ __forceinline__ u16 f2b(float f) {
  union { float f; unsigned int u; } v; v.f = f;
  unsigned int r = v.u + 0x7fffu + ((v.u >> 16) & 1u);
  return (u16)(r >> 16);
}
// y = m / 28 for m < 65536 (magic: 2341 = ceil(2^16/28))
__device__ __forceinline__ int div28(int m) { return (m * 2341) >> 16; }
// y = t / 784 for t < 25088 (magic: 5350 = ceil(2^22/784))
__device__ __forceinline__ int div784(int t) { return (int)(((long long)t * 5350) >> 22); }

// async global->LDS 16B copy. LDS dest is wave-uniform base + lane*16 (linear).
__device__ __forceinline__ void gl_lds16(const u16* g, u16* l) {
  __builtin_amdgcn_global_load_lds(
      (const __attribute__((address_space(1))) unsigned int*)g,
      (__attribute__((address_space(3))) unsigned int*)l, 16, 0, 0);
}

// ---------------- weight convert f32 -> bf16 (4 arrays) ----------------
struct CvtTab { const float* src[4]; u16* dst[4]; int n[4]; };

__global__ __launch_bounds__(256) void k_cvt(CvtTab tab) {
  int a = blockIdx.y;
  int n4 = tab.n[a] >> 2;
  const float4* s = (const float4*)tab.src[a];
  ushort4* d = (ushort4*)tab.dst[a];
  for (int i = blockIdx.x * 256 + threadIdx.x; i < n4; i += gridDim.x * 256) {
    float4 v = s[i];
    ushort4 o;
    o.x = f2b(v.x); o.y = f2b(v.y); o.z = f2b(v.z); o.w = f2b(v.w);
    d[i] = o;
  }
}

// ---------------- abmix: abm[idx][g] = sum_h th1w[g,h]*ab[h,idx] + th1b[g] ----------------
__global__ __launch_bounds__(256) void k_abmix(const float* __restrict__ ab,
                                               const float* __restrict__ th1w,
                                               const float* __restrict__ th1b,
                                               float* __restrict__ abm) {
  int t = blockIdx.x * 256 + threadIdx.x;
  if (t >= 8 * N_) return;
  int i = t >> 3, g = t & 7;
  float s = th1b[g];
  for (int h = 0; h < 8; ++h) s += th1w[g * 8 + h] * ab[h * N_ + i];
  abm[i * 8 + g] = s;
}

// ---------------- K0: transpose x(f32) [b][c][n] -> xT(bf16) [bl][n][c] ----------------
__global__ __launch_bounds__(256) void k_transpose(const float* __restrict__ x,
                                                   u16* __restrict__ xT, int b0) {
  __shared__ u16 tile[64][65];
  int nt = blockIdx.x, ct = blockIdx.y, bl = blockIdx.z;
  int t = threadIdx.x;
  int n0 = nt * 64, c0 = ct * 64;
  const float* xb = x + (size_t)(b0 + bl) * DIM_ * N_;
  int nl = t & 63, cg = t >> 6;
  for (int i = 0; i < 16; ++i) {
    int cl = cg * 16 + i;
    int n = n0 + nl;
    u16 val = 0;
    if (n < N_) val = f2b(xb[(size_t)(c0 + cl) * N_ + n]);
    tile[cl][nl] = val;
  }
  __syncthreads();
  u16* xTb = xT + (size_t)bl * N_ * DIM_;
  int cl = t & 63, ng = t >> 6;
  for (int i = 0; i < 16; ++i) {
    int n2 = n0 + ng * 16 + i;
    if (n2 < N_) xTb[(size_t)n2 * DIM_ + (c0 + cl)] = tile[cl][ng * 16 + i];
  }
}

// ---------------- K1: QKV projection, staged 128x128 tile, BK=64, XOR-swizzled LDS --------
__global__ __launch_bounds__(256) void k_proj(
    const u16* __restrict__ xT,
    const u16* __restrict__ wqb, const u16* __restrict__ wkb, const u16* __restrict__ wvb,
    const float* __restrict__ bq, const float* __restrict__ sq, const float* __restrict__ tq,
    const float* __restrict__ bk, const float* __restrict__ sk, const float* __restrict__ tk,
    const float* __restrict__ bv, const float* __restrict__ sv, const float* __restrict__ tv,
    u16* __restrict__ qb, u16* __restrict__ kb, u16* __restrict__ vb, int ntok) {
  __shared__ u16 ldsA[128 * 64];
  __shared__ u16 ldsB[128 * 64];
  int nt = blockIdx.x, mt = blockIdx.y;
  int t = threadIdx.x;
  int oc0 = mt * 128;
  const u16* Wsrc; const float *bsrc, *ssrc, *tsrc; int obase;
  if (mt < 2)      { Wsrc = wqb; bsrc = bq; ssrc = sq; tsrc = tq; obase = oc0; }
  else if (mt < 4) { Wsrc = wkb; bsrc = bk; ssrc = sk; tsrc = tk; obase = oc0 - 256; }
  else             { Wsrc = wvb; bsrc = bv; ssrc = sv; tsrc = tv; obase = oc0 - 512; }

  int lane = t & 63, wid = t >> 6;
  int wm = wid & 1, wn = wid >> 1;
  int l16 = lane & 15, quad = lane >> 4;

  f32x4 acc[4][4] = {};
  for (int kc = 0; kc < DIM_ / 64; ++kc) {
    __syncthreads();
    #pragma unroll
    for (int j = 0; j < 4; ++j) {
      int s = j * 256 + t;
      int row = s >> 3, ch = s & 7;
      int gc = (ch ^ (row & 7)) * 8;
      gl_lds16(Wsrc + (size_t)(obase + row) * DIM_ + kc * 64 + gc, ldsA + s * 8);
    }
    #pragma unroll
    for (int j = 0; j < 4; ++j) {
      int s = j * 256 + t;
      int row = s >> 3, ch = s & 7;
      int gc = (ch ^ (row & 7)) * 8;
      int tr = nt * 128 + row; if (tr >= ntok) tr = ntok - 1;
      gl_lds16(xT + (size_t)tr * DIM_ + kc * 64 + gc, ldsB + s * 8);
    }
    __syncthreads();
    #pragma unroll
    for (int kc2 = 0; kc2 < 2; ++kc2) {
      s16x8 a[4], b[4];
      #pragma unroll
      for (int mi = 0; mi < 4; ++mi) {
        int row = wm * 64 + mi * 16 + l16;
        int ch = (kc2 * 4 + quad) ^ (l16 & 7);
        a[mi] = *(const s16x8*)&ldsA[row * 64 + ch * 8];
      }
      #pragma unroll
      for (int ni = 0; ni < 4; ++ni) {
        int row = wn * 64 + ni * 16 + l16;
        int ch = (kc2 * 4 + quad) ^ (l16 & 7);
        b[ni] = *(const s16x8*)&ldsB[row * 64 + ch * 8];
      }
      #pragma unroll
      for (int mi = 0; mi < 4; ++mi)
        #pragma unroll
        for (int ni = 0; ni < 4; ++ni)
          acc[mi][ni] = __builtin_amdgcn_mfma_f32_16x16x32_bf16(a[mi], b[ni], acc[mi][ni], 0, 0, 0);
    }
  }
  for (int mi = 0; mi < 4; ++mi)
    for (int ni = 0; ni < 4; ++ni) {
      int row0 = wm * 64 + mi * 16 + quad * 4;
      int tg = nt * 128 + wn * 64 + ni * 16 + l16;
      if (tg >= ntok) continue;
      int bl = div784(tg);
      int col = tg - bl * N_;
      int ol0 = obase + row0;
      float4 bb = *(const float4*)&bsrc[ol0];
      float4 ss = *(const float4*)&ssrc[ol0];
      float4 tt = *(const float4*)&tsrc[ol0];
      float v0 = (acc[mi][ni][0] + bb.x) * ss.x + tt.x;
      float v1 = (acc[mi][ni][1] + bb.y) * ss.y + tt.y;
      float v2 = (acc[mi][ni][2] + bb.z) * ss.z + tt.z;
      float v3 = (acc[mi][ni][3] + bb.w) * ss.w + tt.w;
      int oc = oc0 + row0;
      if (oc < 512) {
        int h = (oc & 255) >> 5, c0 = oc & 31;
        u16* dst = (oc < 256) ? qb : kb;
        ushort4 o;
        o.x = f2b(v0); o.y = f2b(v1); o.z = f2b(v2); o.w = f2b(v3);
        *(ushort4*)&dst[(((size_t)bl * H_ + h) * N_ + col) * KD_ + c0] = o;
      } else {
        int ch = oc - 512;
        vb[((size_t)bl * DH_ + ch) * N_ + col] = f2b(v0);
        vb[((size_t)bl * DH_ + ch + 1) * N_ + col] = f2b(v1);
        vb[((size_t)bl * DH_ + ch + 2) * N_ + col] = f2b(v2);
        vb[((size_t)bl * DH_ + ch + 3) * N_ + col] = f2b(v3);
      }
    }
}

// ---------------- K2: depthwise 3x3 conv + affine; wave-per-channel ----------------
__global__ __launch_bounds__(256) void k_dwconv(
    const u16* __restrict__ vb, const float* __restrict__ Wvl,
    const float* __restrict__ bvl, const float* __restrict__ svl, const float* __restrict__ tvl,
    u16* __restrict__ vlb) {
  __shared__ u16 img[4][N_];
  int cg = blockIdx.x, bl = blockIdx.y;
  int t = threadIdx.x;
  int wid = t >> 6, lane = t & 63;
  int ch = cg * 4 + wid;
  const u16* vp = vb + ((size_t)bl * DH_ + ch) * N_;
  for (int i = lane; i < N_; i += 64) img[wid][i] = vp[i];
  __syncthreads();
  float w[9];
  for (int i = 0; i < 9; ++i) w[i] = Wvl[ch * 9 + i];
  float bias = bvl[ch], sc = svl[ch], sh = tvl[ch];
  u16* op = vlb + ((size_t)bl * DH_ + ch) * N_;
  for (int p = lane; p < N_; p += 64) {
    int y = p / R_, x = p - y * R_;
    float acc = 0.f;
    #pragma unroll
    for (int dy = -1; dy <= 1; ++dy) {
      int yy = y + dy;
      if (yy < 0 || yy >= R_) continue;
      #pragma unroll
      for (int dx = -1; dx <= 1; ++dx) {
        int xx = x + dx;
        if (xx < 0 || xx >= R_) continue;
        acc += b2f(img[wid][yy * R_ + xx]) * w[(dy + 1) * 3 + (dx + 1)];
      }
    }
    op[p] = f2b((acc + bias) * sc + sh);
  }
}

// ---------------- K3a: attention pass 1 -------------------------------------------------
// Grid (49 ntile, 4 msplit, G). Computes e = exp(mix1(QK^T)+abmix) for its m-quarter,
// accumulates partial L into Lbuf[mo][bl][g][n] AND stores e (bf16) into EP g-planes.
// Scalar fmaf mix1 (84 VGPR proven; r9 ERRATA: f32x4 vector exprs -> 216 VGPR, 2.3x slower).
__global__ __launch_bounds__(256) void k_attn1(
    const u16* __restrict__ qb, const u16* __restrict__ kb,
    const float* __restrict__ abm, const float* __restrict__ th1w,
    float* __restrict__ Lbuf, u16* __restrict__ EP) {
  __shared__ float abms[N_ * 8];
  __shared__ float w1Ts[64];
  __shared__ float lred[4][8][16];
  int nt = blockIdx.x, mo = blockIdx.y, bl = blockIdx.z;
  int G = gridDim.z;
  int t = threadIdx.x;
  for (int i = t; i < N_ * 8; i += 256) abms[i] = abm[i];
  if (t < 64) w1Ts[(t & 7) * 8 + (t >> 3)] = th1w[t];
  __syncthreads();

  int lane = t & 63, wid = t >> 6;
  int l16 = lane & 15, quad = lane >> 4;
  int koff = quad * 8;
  int n_g = nt * 16 + l16;             // < 784 always (49*16=784)
  int yn = div28(n_g), xn = n_g - yn * R_;
  size_t blb = (size_t)bl * H_ * N_;

  s16x8 qf[8];
  #pragma unroll
  for (int h = 0; h < 8; ++h)
    qf[h] = *(const s16x8*)&qb[(blb + (size_t)h * N_ + n_g) * KD_ + koff];

  float Lp[8] = {};
  #pragma unroll 1
  for (int s = mo; s < 13; s += 4) {
    int mb = s * 64 + wid * 16;
    if (mb >= N_) continue;           // wave-uniform
    f32x4 sm8[8] = {};
    #pragma unroll
    for (int h = 0; h < 8; ++h) {
      s16x8 af = *(const s16x8*)&kb[(blb + (size_t)h * N_ + mb + l16) * KD_ + koff];
      f32x4 acc = {};
      acc = __builtin_amdgcn_mfma_f32_16x16x32_bf16(af, qf[h], acc, 0, 0, 0);
      f32x4 wA = *(const f32x4*)&w1Ts[h * 8];
      f32x4 wB = *(const f32x4*)&w1Ts[h * 8 + 4];
      #pragma unroll
      for (int g = 0; g < 4; ++g)
        #pragma unroll
        for (int r = 0; r < 4; ++r) {
          sm8[g][r] = fmaf(wA[g], acc[r], sm8[g][r]);
          sm8[g + 4][r] = fmaf(wB[g], acc[r], sm8[g + 4][r]);
        }
    }
    int mc = mb + quad * 4;
    int idx4[4];
    #pragma unroll
    for (int r = 0; r < 4; ++r) {
      int m = mc + r;
      int ym = div28(m), xm = m - ym * R_;
      int dy = yn - ym; dy = dy < 0 ? -dy : dy;
      int dx = xn - xm; dx = dx < 0 ? -dx : dx;
      idx4[r] = (dy * R_ + dx) * 8;
    }
    #pragma unroll
    for (int g = 0; g < 8; ++g) {
      float e0 = __expf(fmaf(sm8[g][0], SCALE_, abms[idx4[0] + g]));
      float e1 = __expf(fmaf(sm8[g][1], SCALE_, abms[idx4[1] + g]));
      float e2 = __expf(fmaf(sm8[g][2], SCALE_, abms[idx4[2] + g]));
      float e3 = __expf(fmaf(sm8[g][3], SCALE_, abms[idx4[3] + g]));
      Lp[g] += (e0 + e1) + (e2 + e3);
      ushort4 ov;
      ov.x = f2b(e0); ov.y = f2b(e1); ov.z = f2b(e2); ov.w = f2b(e3);
      *(ushort4*)&EP[((size_t)(bl * 8 + g) * N_ + n_g) * PSTR_ + mc] = ov;
    }
  }
  #pragma unroll
  for (int g = 0; g < 8; ++g) {
    Lp[g] += __shfl_xor(Lp[g], 16);
    Lp[g] += __shfl_xor(Lp[g], 32);
  }
  if (quad == 0)
    #pragma unroll
    for (int g = 0; g < 8; ++g) lred[wid][g][l16] = Lp[g];
  __syncthreads();
  if (t < 128) {
    int g = t >> 4, nn = t & 15;
    float L = lred[0][g][nn] + lred[1][g][nn] + lred[2][g][nn] + lred[3][g][nn];
    Lbuf[(((size_t)mo * G + bl) * 8 + g) * N_ + nt * 16 + nn] = L;
  }
}

// ---------------- K3b: in-place normalize + th2-mix: EP g-planes -> P f-planes ----------
// Grid (784 n, G). Block handles one (bl,n) row; thread t = m4 group (208 used).
// Reads e[8g] at its mc, writes P[8f] at same addresses (read-before-write per thread;
// threads touch disjoint mc -> race-free). Pad m in [784,832) written zero for k_pv.
__global__ __launch_bounds__(256) void k_attn2(
    const float* __restrict__ Lbuf, const float* __restrict__ th2w,
    const float* __restrict__ th2b, u16* __restrict__ EP, int G) {
  __shared__ float w2s[64], b2s[8], linv[8];
  int n = blockIdx.x, bl = blockIdx.y;
  int t = threadIdx.x;
  if (t < 64) w2s[t] = th2w[t];
  if (t < 8) {
    b2s[t] = th2b[t];
    float L = 0.f;
    for (int p = 0; p < 4; ++p)
      L += Lbuf[(((size_t)p * G + bl) * 8 + t) * N_ + n];
    linv[t] = 1.f / L;
  }
  __syncthreads();
  if (t >= PSTR_ / 4) return;
  int mc = t * 4;
  const size_t pstr = (size_t)N_ * PSTR_;
  size_t base = ((size_t)bl * 8 * N_ + n) * (size_t)PSTR_ + mc;
  if (mc >= N_) {
    ushort4 z = {0, 0, 0, 0};
    #pragma unroll
    for (int f = 0; f < 8; ++f) *(ushort4*)&EP[base + (size_t)f * pstr] = z;
    return;
  }
  float e[8][4];
  #pragma unroll
  for (int g = 0; g < 8; ++g) {
    ushort4 raw = *(const ushort4*)&EP[base + (size_t)g * pstr];
    float li = linv[g];
    e[g][0] = b2f(raw.x) * li; e[g][1] = b2f(raw.y) * li;
    e[g][2] = b2f(raw.z) * li; e[g][3] = b2f(raw.w) * li;
  }
  #pragma unroll 1
  for (int f = 0; f < 8; ++f) {
    float b = b2s[f];
    float o0 = b, o1 = b, o2 = b, o3 = b;
    #pragma unroll
    for (int g = 0; g < 8; ++g) {
      float w = w2s[f * 8 + g];
      o0 = fmaf(w, e[g][0], o0); o1 = fmaf(w, e[g][1], o1);
      o2 = fmaf(w, e[g][2], o2); o3 = fmaf(w, e[g][3], o3);
    }
    ushort4 ov;
    ov.x = f2b(o0); ov.y = f2b(o1); ov.z = f2b(o2); ov.w = f2b(o3);
    *(ushort4*)&EP[base + (size_t)f * pstr] = ov;
  }
}

// ---------------- K5: O' = relu(attn @ V + vl), staged, K=832 (P zero-padded) -------------
// A = V (rows d=128), B = P (rows n, stride PSTR_). acc row=d, col=n.
__global__ __launch_bounds__(256) void k_pv(
    const u16* __restrict__ P, const u16* __restrict__ vb, const u16* __restrict__ vlb,
    u16* __restrict__ ob, int n0, int NC) {
  __shared__ u16 ldsA[128 * 64];
  __shared__ u16 ldsB[128 * 64];
  int ntl = blockIdx.x, z = blockIdx.z;
  int bl = z >> 3, f = z & 7;
  int t = threadIdx.x;
  int lane = t & 63, wid = t >> 6;
  int wm = wid & 1, wn = wid >> 1;
  int l16 = lane & 15, quad = lane >> 4;

  const u16* vsrc = vb + ((size_t)bl * DH_ + f * D_) * N_;
  const u16* asrc = P + ((size_t)bl * H_ + f) * (size_t)NC * PSTR_;

  f32x4 acc[4][4] = {};
  for (int kc = 0; kc < PSTR_ / 64; ++kc) {
    __syncthreads();
    #pragma unroll
    for (int j = 0; j < 4; ++j) {
      int s = j * 256 + t;
      int row = s >> 3, ch = s & 7;
      int gc = (ch ^ (row & 7)) * 8;
      gl_lds16(vsrc + (size_t)row * N_ + kc * 64 + gc, ldsA + s * 8);
    }
    #pragma unroll
    for (int j = 0; j < 4; ++j) {
      int s = j * 256 + t;
      int row = s >> 3, ch = s & 7;
      int gc = (ch ^ (row & 7)) * 8;
      int nr = ntl * 128 + row; if (nr >= NC) nr = NC - 1;
      gl_lds16(asrc + (size_t)nr * PSTR_ + kc * 64 + gc, ldsB + s * 8);
    }
    __syncthreads();
    #pragma unroll
    for (int kc2 = 0; kc2 < 2; ++kc2) {
      s16x8 a[4], b[4];
      #pragma unroll
      for (int mi = 0; mi < 4; ++mi) {
        int row = wm * 64 + mi * 16 + l16;
        int ch = (kc2 * 4 + quad) ^ (l16 & 7);
        a[mi] = *(const s16x8*)&ldsA[row * 64 + ch * 8];
      }
      #pragma unroll
      for (int ni = 0; ni < 4; ++ni) {
        int row = wn * 64 + ni * 16 + l16;
        int ch = (kc2 * 4 + quad) ^ (l16 & 7);
        b[ni] = *(const s16x8*)&ldsB[row * 64 + ch * 8];
      }
      #pragma unroll
      for (int mi = 0; mi < 4; ++mi)
        #pragma unroll
        for (int ni = 0; ni < 4; ++ni)
          acc[mi][ni] = __builtin_amdgcn_mfma_f32_16x16x32_bf16(a[mi], b[ni], acc[mi][ni], 0, 0, 0);
    }
  }
  for (int mi = 0; mi < 4; ++mi)
    for (int ni = 0; ni < 4; ++ni) {
      int row = wm * 64 + mi * 16 + quad * 4;
      int col = wn * 64 + ni * 16 + l16;
      int nloc = ntl * 128 + col;
      if (nloc >= NC || (n0 + nloc) >= N_) continue;
      int ch = f * D_ + row;
      size_t vaddr = ((size_t)bl * DH_ + ch) * N_ + (n0 + nloc);
      float o0 = acc[mi][ni][0] + b2f(vlb[vaddr]);
      float o1 = acc[mi][ni][1] + b2f(vlb[vaddr + N_]);
      float o2 = acc[mi][ni][2] + b2f(vlb[vaddr + 2 * N_]);
      float o3 = acc[mi][ni][3] + b2f(vlb[vaddr + 3 * N_]);
      size_t addr = ((size_t)bl * N_ + (n0 + nloc)) * DH_ + ch;
      ushort4 o4;
      o4.x = f2b(o0 > 0.f ? o0 : 0.f);
      o4.y = f2b(o1 > 0.f ? o1 : 0.f);
      o4.z = f2b(o2 > 0.f ? o2 : 0.f);
      o4.w = f2b(o3 > 0.f ? o3 : 0.f);
      *(ushort4*)&ob[addr] = o4;
    }
}

// ---------------- K6: out = affine(Wp @ O' + bp), staged, f32 out ----------------
__global__ __launch_bounds__(256) void k_outproj(
    const u16* __restrict__ ob, const u16* __restrict__ wpb,
    const float* __restrict__ bp, const float* __restrict__ sp, const float* __restrict__ tp,
    float* __restrict__ out, int b0, int ntok) {
  __shared__ u16 ldsA[128 * 64];
  __shared__ u16 ldsB[128 * 64];
  int nt = blockIdx.x, mt = blockIdx.y;
  int t = threadIdx.x;
  int lane = t & 63, wid = t >> 6;
  int wm = wid & 1, wn = wid >> 1;
  int l16 = lane & 15, quad = lane >> 4;

  f32x4 acc[4][4] = {};
  for (int kc = 0; kc < DH_ / 64; ++kc) {
    __syncthreads();
    #pragma unroll
    for (int j = 0; j < 4; ++j) {
      int s = j * 256 + t;
      int row = s >> 3, ch = s & 7;
      int gc = (ch ^ (row & 7)) * 8;
      gl_lds16(wpb + (size_t)(mt * 128 + row) * DH_ + kc * 64 + gc, ldsA + s * 8);
    }
    #pragma unroll
    for (int j = 0; j < 4; ++j) {
      int s = j * 256 + t;
      int row = s >> 3, ch = s & 7;
      int gc = (ch ^ (row & 7)) * 8;
      int tr = nt * 128 + row; if (tr >= ntok) tr = ntok - 1;
      gl_lds16(ob + (size_t)tr * DH_ + kc * 64 + gc, ldsB + s * 8);
    }
    __syncthreads();
    #pragma unroll
    for (int kc2 = 0; kc2 < 2; ++kc2) {
      s16x8 a[4], b[4];
      #pragma unroll
      for (int mi = 0; mi < 4; ++mi) {
        int row = wm * 64 + mi * 16 + l16;
        int ch = (kc2 * 4 + quad) ^ (l16 & 7);
        a[mi] = *(const s16x8*)&ldsA[row * 64 + ch * 8];
      }
      #pragma unroll
      for (int ni = 0; ni < 4; ++ni) {
        int row = wn * 64 + ni * 16 + l16;
        int ch = (kc2 * 4 + quad) ^ (l16 & 7);
        b[ni] = *(const s16x8*)&ldsB[row * 64 + ch * 8];
      }
      #pragma unroll
      for (int mi = 0; mi < 4; ++mi)
        #pragma unroll
        for (int ni = 0; ni < 4; ++ni)
          acc[mi][ni] = __builtin_amdgcn_mfma_f32_16x16x32_bf16(a[mi], b[ni], acc[mi][ni], 0, 0, 0);
    }
  }
  for (int mi = 0; mi < 4; ++mi)
    for (int ni = 0; ni < 4; ++ni) {
      int row0 = wm * 64 + mi * 16 + quad * 4;
      int tg = nt * 128 + wn * 64 + ni * 16 + l16;
      if (tg >= ntok) continue;
      int bl = div784(tg);
      int n = tg - bl * N_;
      int oc0 = mt * 128 + row0;
      float4 bb = *(const float4*)&bp[oc0];
      float4 ss = *(const float4*)&sp[oc0];
      float4 tt = *(const float4*)&tp[oc0];
      float* o = out + ((size_t)(b0 + bl) * DIM_) * N_ + n;
      o[(size_t)(oc0 + 0) * N_] = (acc[mi][ni][0] + bb.x) * ss.x + tt.x;
      o[(size_t)(oc0 + 1) * N_] = (acc[mi][ni][1] + bb.y) * ss.y + tt.y;
      o[(size_t)(oc0 + 2) * N_] = (acc[mi][ni][2] + bb.z) * ss.z + tt.z;
      o[(size_t)(oc0 + 3) * N_] = (acc[mi][ni][3] + bb.w) * ss.w + tt.w;
    }
}

extern "C" void kernel_launch(void* const* d_in, const int* in_sizes, int n_in,
                              void* d_out, int out_size, void* d_ws, size_t ws_size,
                              hipStream_t stream) {
  (void)in_sizes; (void)n_in; (void)out_size;
  const float* x    = (const float*)d_in[0];
  const float* Wq   = (const float*)d_in[1];
  const float* bq   = (const float*)d_in[2];
  const float* sq   = (const float*)d_in[3];
  const float* tq   = (const float*)d_in[4];
  const float* Wk   = (const float*)d_in[5];
  const float* bk   = (const float*)d_in[6];
  const float* sk   = (const float*)d_in[7];
  const float* tk   = (const float*)d_in[8];
  const float* Wv   = (const float*)d_in[9];
  const float* bv   = (const float*)d_in[10];
  const float* sv   = (const float*)d_in[11];
  const float* tv   = (const float*)d_in[12];
  const float* Wvl  = (const float*)d_in[13];
  const float* bvl  = (const float*)d_in[14];
  const float* svl  = (const float*)d_in[15];
  const float* tvl  = (const float*)d_in[16];
  const float* th1w = (const float*)d_in[17];
  const float* th1b = (const float*)d_in[18];
  const float* th2w = (const float*)d_in[19];
  const float* th2b = (const float*)d_in[20];
  const float* ab   = (const float*)d_in[21];
  const float* Wp   = (const float*)d_in[22];
  const float* bp   = (const float*)d_in[23];
  const float* sp   = (const float*)d_in[24];
  const float* tp   = (const float*)d_in[25];
  float* out = (float*)d_out;

  char* ws = (char*)d_ws;
  size_t off = 0;
  auto alloc = [&](size_t bytes) -> void* {
    void* p = ws + off;
    off += (bytes + 255) & ~(size_t)255;
    return p;
  };

  u16* wqb = (u16*)alloc((size_t)256 * DIM_ * 2);
  u16* wkb = (u16*)alloc((size_t)256 * DIM_ * 2);
  u16* wvb = (u16*)alloc((size_t)DH_ * DIM_ * 2);
  u16* wpb = (u16*)alloc((size_t)DIM_ * DH_ * 2);
  float* abm = (float*)alloc((size_t)N_ * 8 * 4);
  size_t fixed = off;

  auto footprint = [fixed](int G) -> size_t {
    auto al = [](size_t b) { return (b + 255) & ~(size_t)255; };
    size_t a = fixed;
    a += al((size_t)G * H_ * N_ * KD_ * 2);   // qb
    a += al((size_t)G * H_ * N_ * KD_ * 2);   // kb
    a += al((size_t)G * DH_ * N_ * 2);        // vb
    a += al((size_t)G * DH_ * N_ * 2);        // vlb
    a += al((size_t)G * N_ * DH_ * 2);        // obb
    a += al((size_t)G * N_ * DIM_ * 2);       // xT
    a += al((size_t)4 * G * 8 * N_ * 4);      // Lbuf (4 m-split partials)
    a += al((size_t)G * 8 * N_ * PSTR_ * 2);  // EP (e planes / P planes, full n)
    return a;
  };
  const int Gs[6] = {32, 16, 8, 4, 2, 1};
  int G = 1;
  for (int gi = 0; gi < 6; ++gi)
    if (footprint(Gs[gi]) <= ws_size) { G = Gs[gi]; break; }

  u16* qb  = (u16*)alloc((size_t)G * H_ * N_ * KD_ * 2);
  u16* kb  = (u16*)alloc((size_t)G * H_ * N_ * KD_ * 2);
  u16* vb  = (u16*)alloc((size_t)G * DH_ * N_ * 2);
  u16* vlb = (u16*)alloc((size_t)G * DH_ * N_ * 2);   // [bl][ch][n]
  u16* obb = (u16*)alloc((size_t)G * N_ * DH_ * 2);
  u16* xT  = (u16*)alloc((size_t)G * N_ * DIM_ * 2);
  float* Lbuf = (float*)alloc((size_t)4 * G * 8 * N_ * 4);
  u16* EP  = (u16*)alloc((size_t)G * 8 * N_ * PSTR_ * 2);

  CvtTab ct;
  ct.src[0] = Wq; ct.dst[0] = wqb; ct.n[0] = 256 * DIM_;
  ct.src[1] = Wk; ct.dst[1] = wkb; ct.n[1] = 256 * DIM_;
  ct.src[2] = Wv; ct.dst[2] = wvb; ct.n[2] = DH_ * DIM_;
  ct.src[3] = Wp; ct.dst[3] = wpb; ct.n[3] = DIM_ * DH_;
  hipLaunchKernelGGL(k_cvt, dim3(96, 4), dim3(256), 0, stream, ct);
  hipLaunchKernelGGL(k_abmix, dim3(25), dim3(256), 0, stream, ab, th1w, th1b, abm);

  int ntok = G * N_;
  int ttiles = (ntok + 127) / 128;
  for (int b0 = 0; b0 < B_; b0 += G) {
    hipLaunchKernelGGL(k_transpose, dim3(13, 6, G), dim3(256), 0, stream, x, xT, b0);
    hipLaunchKernelGGL(k_proj, dim3(ttiles, 12), dim3(256), 0, stream, xT,
                       wqb, wkb, wvb, bq, sq, tq, bk, sk, tk, bv, sv, tv, qb, kb, vb, ntok);
    hipLaunchKernelGGL(k_dwconv, dim3(DH_ / 4, G), dim3(256), 0, stream,
                       vb, Wvl, bvl, svl, tvl, vlb);
    hipLaunchKernelGGL(k_attn1, dim3(49, 4, G), dim3(256), 0, stream,
                       qb, kb, abm, th1w, Lbuf, EP);
    hipLaunchKernelGGL(k_attn2, dim3(N_, G), dim3(256), 0, stream,
                       Lbuf, th2w, th2b, EP, G);
    hipLaunchKernelGGL(k_pv, dim3(7, 1, G * H_), dim3(256), 0, stream,
                       EP, vb, vlb, obb, 0, N_);
    hipLaunchKernelGGL(k_outproj, dim3(ttiles, 3), dim3(256), 0, stream,
                       obb, wpb, bp, sp, tp, out, b0, ntok);
  }
}

// Round 12
// 813.615 us; speedup vs baseline: 1.7142x; 1.0783x over previous
//
#include <hip/hip_runtime.h>
#include <hip/hip_bf16.h>

#define B_ 32
#define DIM_ 384
#define R_ 28
#define N_ 784
#define H_ 8
#define KD_ 32
#define D_ 128
#define DH_ 1024
#define PSTR_ 832
#define SCALE_ 0.17677669529663687f

typedef unsigned short u16;
typedef __attribute__((ext_vector_type(4))) float f32x4;
typedef __attribute__((ext_vector_type(8))) short s16x8;

__device__ __forceinline__ float b2f(u16 b) {
  union { unsigned int u; float f; } v; v.u = ((unsigned int)b) << 16; return v.f;
}
__device__ __forceinline__ u16 f2b(float f) {
  union { float f; unsigned int u; } v; v.f = f;
  unsigned int r = v.u + 0x7fffu + ((v.u >> 16) & 1u);
  return (u16)(r >> 16);
}
// y = m / 28 for m < 65536 (magic: 2341 = ceil(2^16/28))
__device__ __forceinline__ int div28(int m) { return (m * 2341) >> 16; }
// y = t / 784 for t < 25088 (magic: 5350 = ceil(2^22/784))
__device__ __forceinline__ int div784(int t) { return (int)(((long long)t * 5350) >> 22); }

// async global->LDS 16B copy. LDS dest is wave-uniform base + lane*16 (linear).
__device__ __forceinline__ void gl_lds16(const u16* g, u16* l) {
  __builtin_amdgcn_global_load_lds(
      (const __attribute__((address_space(1))) unsigned int*)g,
      (__attribute__((address_space(3))) unsigned int*)l, 16, 0, 0);
}

// ---------------- weight convert f32 -> bf16 (4 arrays) ----------------
struct CvtTab { const float* src[4]; u16* dst[4]; int n[4]; };

__global__ __launch_bounds__(256) void k_cvt(CvtTab tab) {
  int a = blockIdx.y;
  int n4 = tab.n[a] >> 2;
  const float4* s = (const float4*)tab.src[a];
  ushort4* d = (ushort4*)tab.dst[a];
  for (int i = blockIdx.x * 256 + threadIdx.x; i < n4; i += gridDim.x * 256) {
    float4 v = s[i];
    ushort4 o;
    o.x = f2b(v.x); o.y = f2b(v.y); o.z = f2b(v.z); o.w = f2b(v.w);
    d[i] = o;
  }
}

// ---------------- abmix: abm[idx][g] = sum_h th1w[g,h]*ab[h,idx] + th1b[g] ----------------
__global__ __launch_bounds__(256) void k_abmix(const float* __restrict__ ab,
                                               const float* __restrict__ th1w,
                                               const float* __restrict__ th1b,
                                               float* __restrict__ abm) {
  int t = blockIdx.x * 256 + threadIdx.x;
  if (t >= 8 * N_) return;
  int i = t >> 3, g = t & 7;
  float s = th1b[g];
  for (int h = 0; h < 8; ++h) s += th1w[g * 8 + h] * ab[h * N_ + i];
  abm[i * 8 + g] = s;
}

// ---------------- K0: transpose x(f32) [b][c][n] -> xT(bf16) [bl][n][c] ----------------
__global__ __launch_bounds__(256) void k_transpose(const float* __restrict__ x,
                                                   u16* __restrict__ xT, int b0) {
  __shared__ u16 tile[64][65];
  int nt = blockIdx.x, ct = blockIdx.y, bl = blockIdx.z;
  int t = threadIdx.x;
  int n0 = nt * 64, c0 = ct * 64;
  const float* xb = x + (size_t)(b0 + bl) * DIM_ * N_;
  int nl = t & 63, cg = t >> 6;
  for (int i = 0; i < 16; ++i) {
    int cl = cg * 16 + i;
    int n = n0 + nl;
    u16 val = 0;
    if (n < N_) val = f2b(xb[(size_t)(c0 + cl) * N_ + n]);
    tile[cl][nl] = val;
  }
  __syncthreads();
  u16* xTb = xT + (size_t)bl * N_ * DIM_;
  int cl = t & 63, ng = t >> 6;
  for (int i = 0; i < 16; ++i) {
    int n2 = n0 + ng * 16 + i;
    if (n2 < N_) xTb[(size_t)n2 * DIM_ + (c0 + cl)] = tile[cl][ng * 16 + i];
  }
}

// ---------------- K1: QKV projection, staged 128x128 tile, BK=64, XOR-swizzled LDS --------
__global__ __launch_bounds__(256) void k_proj(
    const u16* __restrict__ xT,
    const u16* __restrict__ wqb, const u16* __restrict__ wkb, const u16* __restrict__ wvb,
    const float* __restrict__ bq, const float* __restrict__ sq, const float* __restrict__ tq,
    const float* __restrict__ bk, const float* __restrict__ sk, const float* __restrict__ tk,
    const float* __restrict__ bv, const float* __restrict__ sv, const float* __restrict__ tv,
    u16* __restrict__ qb, u16* __restrict__ kb, u16* __restrict__ vb, int ntok) {
  __shared__ u16 ldsA[128 * 64];
  __shared__ u16 ldsB[128 * 64];
  int nt = blockIdx.x, mt = blockIdx.y;
  int t = threadIdx.x;
  int oc0 = mt * 128;
  const u16* Wsrc; const float *bsrc, *ssrc, *tsrc; int obase;
  if (mt < 2)      { Wsrc = wqb; bsrc = bq; ssrc = sq; tsrc = tq; obase = oc0; }
  else if (mt < 4) { Wsrc = wkb; bsrc = bk; ssrc = sk; tsrc = tk; obase = oc0 - 256; }
  else             { Wsrc = wvb; bsrc = bv; ssrc = sv; tsrc = tv; obase = oc0 - 512; }

  int lane = t & 63, wid = t >> 6;
  int wm = wid & 1, wn = wid >> 1;
  int l16 = lane & 15, quad = lane >> 4;

  f32x4 acc[4][4] = {};
  for (int kc = 0; kc < DIM_ / 64; ++kc) {
    __syncthreads();
    #pragma unroll
    for (int j = 0; j < 4; ++j) {
      int s = j * 256 + t;
      int row = s >> 3, ch = s & 7;
      int gc = (ch ^ (row & 7)) * 8;
      gl_lds16(Wsrc + (size_t)(obase + row) * DIM_ + kc * 64 + gc, ldsA + s * 8);
    }
    #pragma unroll
    for (int j = 0; j < 4; ++j) {
      int s = j * 256 + t;
      int row = s >> 3, ch = s & 7;
      int gc = (ch ^ (row & 7)) * 8;
      int tr = nt * 128 + row; if (tr >= ntok) tr = ntok - 1;
      gl_lds16(xT + (size_t)tr * DIM_ + kc * 64 + gc, ldsB + s * 8);
    }
    __syncthreads();
    #pragma unroll
    for (int kc2 = 0; kc2 < 2; ++kc2) {
      s16x8 a[4], b[4];
      #pragma unroll
      for (int mi = 0; mi < 4; ++mi) {
        int row = wm * 64 + mi * 16 + l16;
        int ch = (kc2 * 4 + quad) ^ (l16 & 7);
        a[mi] = *(const s16x8*)&ldsA[row * 64 + ch * 8];
      }
      #pragma unroll
      for (int ni = 0; ni < 4; ++ni) {
        int row = wn * 64 + ni * 16 + l16;
        int ch = (kc2 * 4 + quad) ^ (l16 & 7);
        b[ni] = *(const s16x8*)&ldsB[row * 64 + ch * 8];
      }
      #pragma unroll
      for (int mi = 0; mi < 4; ++mi)
        #pragma unroll
        for (int ni = 0; ni < 4; ++ni)
          acc[mi][ni] = __builtin_amdgcn_mfma_f32_16x16x32_bf16(a[mi], b[ni], acc[mi][ni], 0, 0, 0);
    }
  }
  for (int mi = 0; mi < 4; ++mi)
    for (int ni = 0; ni < 4; ++ni) {
      int row0 = wm * 64 + mi * 16 + quad * 4;
      int tg = nt * 128 + wn * 64 + ni * 16 + l16;
      if (tg >= ntok) continue;
      int bl = div784(tg);
      int col = tg - bl * N_;
      int ol0 = obase + row0;
      float4 bb = *(const float4*)&bsrc[ol0];
      float4 ss = *(const float4*)&ssrc[ol0];
      float4 tt = *(const float4*)&tsrc[ol0];
      float v0 = (acc[mi][ni][0] + bb.x) * ss.x + tt.x;
      float v1 = (acc[mi][ni][1] + bb.y) * ss.y + tt.y;
      float v2 = (acc[mi][ni][2] + bb.z) * ss.z + tt.z;
      float v3 = (acc[mi][ni][3] + bb.w) * ss.w + tt.w;
      int oc = oc0 + row0;
      if (oc < 512) {
        int h = (oc & 255) >> 5, c0 = oc & 31;
        u16* dst = (oc < 256) ? qb : kb;
        ushort4 o;
        o.x = f2b(v0); o.y = f2b(v1); o.z = f2b(v2); o.w = f2b(v3);
        *(ushort4*)&dst[(((size_t)bl * H_ + h) * N_ + col) * KD_ + c0] = o;
      } else {
        int ch = oc - 512;
        vb[((size_t)bl * DH_ + ch) * N_ + col] = f2b(v0);
        vb[((size_t)bl * DH_ + ch + 1) * N_ + col] = f2b(v1);
        vb[((size_t)bl * DH_ + ch + 2) * N_ + col] = f2b(v2);
        vb[((size_t)bl * DH_ + ch + 3) * N_ + col] = f2b(v3);
      }
    }
}

// ---------------- K2: depthwise 3x3 conv + affine; wave-per-channel ----------------
__global__ __launch_bounds__(256) void k_dwconv(
    const u16* __restrict__ vb, const float* __restrict__ Wvl,
    const float* __restrict__ bvl, const float* __restrict__ svl, const float* __restrict__ tvl,
    u16* __restrict__ vlb) {
  __shared__ u16 img[4][N_];
  int cg = blockIdx.x, bl = blockIdx.y;
  int t = threadIdx.x;
  int wid = t >> 6, lane = t & 63;
  int ch = cg * 4 + wid;
  const u16* vp = vb + ((size_t)bl * DH_ + ch) * N_;
  for (int i = lane; i < N_; i += 64) img[wid][i] = vp[i];
  __syncthreads();
  float w[9];
  for (int i = 0; i < 9; ++i) w[i] = Wvl[ch * 9 + i];
  float bias = bvl[ch], sc = svl[ch], sh = tvl[ch];
  u16* op = vlb + ((size_t)bl * DH_ + ch) * N_;
  for (int p = lane; p < N_; p += 64) {
    int y = p / R_, x = p - y * R_;
    float acc = 0.f;
    #pragma unroll
    for (int dy = -1; dy <= 1; ++dy) {
      int yy = y + dy;
      if (yy < 0 || yy >= R_) continue;
      #pragma unroll
      for (int dx = -1; dx <= 1; ++dx) {
        int xx = x + dx;
        if (xx < 0 || xx >= R_) continue;
        acc += b2f(img[wid][yy * R_ + xx]) * w[(dy + 1) * 3 + (dx + 1)];
      }
    }
    op[p] = f2b((acc + bias) * sc + sh);
  }
}

// ---------------- K3a: attention pass 1 -------------------------------------------------
// Grid (49 ntile, MO msplit, G). Computes e = exp(mix1(QK^T)+abmix) for its m-slice,
// accumulates partial L into Lbuf[mo][bl][g][n] AND stores e (bf16) into EP g-planes.
// Scalar fmaf mix1 (84-120 VGPR proven; r9 ERRATA: f32x4 vector exprs -> 216 VGPR, 2.3x slower).
// MO adaptive via gridDim.y (r11: G=8 -> MO=8 for overlap; G>=16 -> MO=4).
__global__ __launch_bounds__(256) void k_attn1(
    const u16* __restrict__ qb, const u16* __restrict__ kb,
    const float* __restrict__ abm, const float* __restrict__ th1w,
    float* __restrict__ Lbuf, u16* __restrict__ EP) {
  __shared__ float abms[N_ * 8];
  __shared__ float w1Ts[64];
  __shared__ float lred[4][8][16];
  int nt = blockIdx.x, mo = blockIdx.y, bl = blockIdx.z;
  int MO = gridDim.y;
  int G = gridDim.z;
  int t = threadIdx.x;
  for (int i = t; i < N_ * 8; i += 256) abms[i] = abm[i];
  if (t < 64) w1Ts[(t & 7) * 8 + (t >> 3)] = th1w[t];
  __syncthreads();

  int lane = t & 63, wid = t >> 6;
  int l16 = lane & 15, quad = lane >> 4;
  int koff = quad * 8;
  int n_g = nt * 16 + l16;             // < 784 always (49*16=784)
  int yn = div28(n_g), xn = n_g - yn * R_;
  size_t blb = (size_t)bl * H_ * N_;

  s16x8 qf[8];
  #pragma unroll
  for (int h = 0; h < 8; ++h)
    qf[h] = *(const s16x8*)&qb[(blb + (size_t)h * N_ + n_g) * KD_ + koff];

  float Lp[8] = {};
  #pragma unroll 1
  for (int s = mo; s < 13; s += MO) {
    int mb = s * 64 + wid * 16;
    if (mb >= N_) continue;           // wave-uniform
    f32x4 sm8[8] = {};
    #pragma unroll
    for (int h = 0; h < 8; ++h) {
      s16x8 af = *(const s16x8*)&kb[(blb + (size_t)h * N_ + mb + l16) * KD_ + koff];
      f32x4 acc = {};
      acc = __builtin_amdgcn_mfma_f32_16x16x32_bf16(af, qf[h], acc, 0, 0, 0);
      f32x4 wA = *(const f32x4*)&w1Ts[h * 8];
      f32x4 wB = *(const f32x4*)&w1Ts[h * 8 + 4];
      #pragma unroll
      for (int g = 0; g < 4; ++g)
        #pragma unroll
        for (int r = 0; r < 4; ++r) {
          sm8[g][r] = fmaf(wA[g], acc[r], sm8[g][r]);
          sm8[g + 4][r] = fmaf(wB[g], acc[r], sm8[g + 4][r]);
        }
    }
    int mc = mb + quad * 4;
    int idx4[4];
    #pragma unroll
    for (int r = 0; r < 4; ++r) {
      int m = mc + r;
      int ym = div28(m), xm = m - ym * R_;
      int dy = yn - ym; dy = dy < 0 ? -dy : dy;
      int dx = xn - xm; dx = dx < 0 ? -dx : dx;
      idx4[r] = (dy * R_ + dx) * 8;
    }
    #pragma unroll
    for (int g = 0; g < 8; ++g) {
      float e0 = __expf(fmaf(sm8[g][0], SCALE_, abms[idx4[0] + g]));
      float e1 = __expf(fmaf(sm8[g][1], SCALE_, abms[idx4[1] + g]));
      float e2 = __expf(fmaf(sm8[g][2], SCALE_, abms[idx4[2] + g]));
      float e3 = __expf(fmaf(sm8[g][3], SCALE_, abms[idx4[3] + g]));
      Lp[g] += (e0 + e1) + (e2 + e3);
      ushort4 ov;
      ov.x = f2b(e0); ov.y = f2b(e1); ov.z = f2b(e2); ov.w = f2b(e3);
      *(ushort4*)&EP[((size_t)(bl * 8 + g) * N_ + n_g) * PSTR_ + mc] = ov;
    }
  }
  #pragma unroll
  for (int g = 0; g < 8; ++g) {
    Lp[g] += __shfl_xor(Lp[g], 16);
    Lp[g] += __shfl_xor(Lp[g], 32);
  }
  if (quad == 0)
    #pragma unroll
    for (int g = 0; g < 8; ++g) lred[wid][g][l16] = Lp[g];
  __syncthreads();
  if (t < 128) {
    int g = t >> 4, nn = t & 15;
    float L = lred[0][g][nn] + lred[1][g][nn] + lred[2][g][nn] + lred[3][g][nn];
    Lbuf[(((size_t)mo * G + bl) * 8 + g) * N_ + nt * 16 + nn] = L;
  }
}

// ---------------- K3b: in-place normalize + th2-mix: EP g-planes -> P f-planes ----------
// Grid (784 n, G). Block handles one (bl,n) row; thread t = m4 group (208 used).
// Reads e[8g] at its mc, writes P[8f] at same addresses (read-before-write per thread;
// threads touch disjoint mc -> race-free). Pad m in [784,832) written zero for k_pv.
__global__ __launch_bounds__(256) void k_attn2(
    const float* __restrict__ Lbuf, const float* __restrict__ th2w,
    const float* __restrict__ th2b, u16* __restrict__ EP, int G, int MO) {
  __shared__ float w2s[64], b2s[8], linv[8];
  int n = blockIdx.x, bl = blockIdx.y;
  int t = threadIdx.x;
  if (t < 64) w2s[t] = th2w[t];
  if (t < 8) {
    b2s[t] = th2b[t];
    float L = 0.f;
    for (int p = 0; p < MO; ++p)
      L += Lbuf[(((size_t)p * G + bl) * 8 + t) * N_ + n];
    linv[t] = 1.f / L;
  }
  __syncthreads();
  if (t >= PSTR_ / 4) return;
  int mc = t * 4;
  const size_t pstr = (size_t)N_ * PSTR_;
  size_t base = ((size_t)bl * 8 * N_ + n) * (size_t)PSTR_ + mc;
  if (mc >= N_) {
    ushort4 z = {0, 0, 0, 0};
    #pragma unroll
    for (int f = 0; f < 8; ++f) *(ushort4*)&EP[base + (size_t)f * pstr] = z;
    return;
  }
  float e[8][4];
  #pragma unroll
  for (int g = 0; g < 8; ++g) {
    ushort4 raw = *(const ushort4*)&EP[base + (size_t)g * pstr];
    float li = linv[g];
    e[g][0] = b2f(raw.x) * li; e[g][1] = b2f(raw.y) * li;
    e[g][2] = b2f(raw.z) * li; e[g][3] = b2f(raw.w) * li;
  }
  #pragma unroll 1
  for (int f = 0; f < 8; ++f) {
    float b = b2s[f];
    float o0 = b, o1 = b, o2 = b, o3 = b;
    #pragma unroll
    for (int g = 0; g < 8; ++g) {
      float w = w2s[f * 8 + g];
      o0 = fmaf(w, e[g][0], o0); o1 = fmaf(w, e[g][1], o1);
      o2 = fmaf(w, e[g][2], o2); o3 = fmaf(w, e[g][3], o3);
    }
    ushort4 ov;
    ov.x = f2b(o0); ov.y = f2b(o1); ov.z = f2b(o2); ov.w = f2b(o3);
    *(ushort4*)&EP[base + (size_t)f * pstr] = ov;
  }
}

// ---------------- K5: O' = relu(attn @ V + vl), staged, K=832 (P zero-padded) -------------
// A = V (rows d=128), B = P (rows n, stride PSTR_). acc row=d, col=n.
__global__ __launch_bounds__(256) void k_pv(
    const u16* __restrict__ P, const u16* __restrict__ vb, const u16* __restrict__ vlb,
    u16* __restrict__ ob, int n0, int NC) {
  __shared__ u16 ldsA[128 * 64];
  __shared__ u16 ldsB[128 * 64];
  int ntl = blockIdx.x, z = blockIdx.z;
  int bl = z >> 3, f = z & 7;
  int t = threadIdx.x;
  int lane = t & 63, wid = t >> 6;
  int wm = wid & 1, wn = wid >> 1;
  int l16 = lane & 15, quad = lane >> 4;

  const u16* vsrc = vb + ((size_t)bl * DH_ + f * D_) * N_;
  const u16* asrc = P + ((size_t)bl * H_ + f) * (size_t)NC * PSTR_;

  f32x4 acc[4][4] = {};
  for (int kc = 0; kc < PSTR_ / 64; ++kc) {
    __syncthreads();
    #pragma unroll
    for (int j = 0; j < 4; ++j) {
      int s = j * 256 + t;
      int row = s >> 3, ch = s & 7;
      int gc = (ch ^ (row & 7)) * 8;
      gl_lds16(vsrc + (size_t)row * N_ + kc * 64 + gc, ldsA + s * 8);
    }
    #pragma unroll
    for (int j = 0; j < 4; ++j) {
      int s = j * 256 + t;
      int row = s >> 3, ch = s & 7;
      int gc = (ch ^ (row & 7)) * 8;
      int nr = ntl * 128 + row; if (nr >= NC) nr = NC - 1;
      gl_lds16(asrc + (size_t)nr * PSTR_ + kc * 64 + gc, ldsB + s * 8);
    }
    __syncthreads();
    #pragma unroll
    for (int kc2 = 0; kc2 < 2; ++kc2) {
      s16x8 a[4], b[4];
      #pragma unroll
      for (int mi = 0; mi < 4; ++mi) {
        int row = wm * 64 + mi * 16 + l16;
        int ch = (kc2 * 4 + quad) ^ (l16 & 7);
        a[mi] = *(const s16x8*)&ldsA[row * 64 + ch * 8];
      }
      #pragma unroll
      for (int ni = 0; ni < 4; ++ni) {
        int row = wn * 64 + ni * 16 + l16;
        int ch = (kc2 * 4 + quad) ^ (l16 & 7);
        b[ni] = *(const s16x8*)&ldsB[row * 64 + ch * 8];
      }
      #pragma unroll
      for (int mi = 0; mi < 4; ++mi)
        #pragma unroll
        for (int ni = 0; ni < 4; ++ni)
          acc[mi][ni] = __builtin_amdgcn_mfma_f32_16x16x32_bf16(a[mi], b[ni], acc[mi][ni], 0, 0, 0);
    }
  }
  for (int mi = 0; mi < 4; ++mi)
    for (int ni = 0; ni < 4; ++ni) {
      int row = wm * 64 + mi * 16 + quad * 4;
      int col = wn * 64 + ni * 16 + l16;
      int nloc = ntl * 128 + col;
      if (nloc >= NC || (n0 + nloc) >= N_) continue;
      int ch = f * D_ + row;
      size_t vaddr = ((size_t)bl * DH_ + ch) * N_ + (n0 + nloc);
      float o0 = acc[mi][ni][0] + b2f(vlb[vaddr]);
      float o1 = acc[mi][ni][1] + b2f(vlb[vaddr + N_]);
      float o2 = acc[mi][ni][2] + b2f(vlb[vaddr + 2 * N_]);
      float o3 = acc[mi][ni][3] + b2f(vlb[vaddr + 3 * N_]);
      size_t addr = ((size_t)bl * N_ + (n0 + nloc)) * DH_ + ch;
      ushort4 o4;
      o4.x = f2b(o0 > 0.f ? o0 : 0.f);
      o4.y = f2b(o1 > 0.f ? o1 : 0.f);
      o4.z = f2b(o2 > 0.f ? o2 : 0.f);
      o4.w = f2b(o3 > 0.f ? o3 : 0.f);
      *(ushort4*)&ob[addr] = o4;
    }
}

// ---------------- K6: out = affine(Wp @ O' + bp), staged, f32 out ----------------
__global__ __launch_bounds__(256) void k_outproj(
    const u16* __restrict__ ob, const u16* __restrict__ wpb,
    const float* __restrict__ bp, const float* __restrict__ sp, const float* __restrict__ tp,
    float* __restrict__ out, int b0, int ntok) {
  __shared__ u16 ldsA[128 * 64];
  __shared__ u16 ldsB[128 * 64];
  int nt = blockIdx.x, mt = blockIdx.y;
  int t = threadIdx.x;
  int lane = t & 63, wid = t >> 6;
  int wm = wid & 1, wn = wid >> 1;
  int l16 = lane & 15, quad = lane >> 4;

  f32x4 acc[4][4] = {};
  for (int kc = 0; kc < DH_ / 64; ++kc) {
    __syncthreads();
    #pragma unroll
    for (int j = 0; j < 4; ++j) {
      int s = j * 256 + t;
      int row = s >> 3, ch = s & 7;
      int gc = (ch ^ (row & 7)) * 8;
      gl_lds16(wpb + (size_t)(mt * 128 + row) * DH_ + kc * 64 + gc, ldsA + s * 8);
    }
    #pragma unroll
    for (int j = 0; j < 4; ++j) {
      int s = j * 256 + t;
      int row = s >> 3, ch = s & 7;
      int gc = (ch ^ (row & 7)) * 8;
      int tr = nt * 128 + row; if (tr >= ntok) tr = ntok - 1;
      gl_lds16(ob + (size_t)tr * DH_ + kc * 64 + gc, ldsB + s * 8);
    }
    __syncthreads();
    #pragma unroll
    for (int kc2 = 0; kc2 < 2; ++kc2) {
      s16x8 a[4], b[4];
      #pragma unroll
      for (int mi = 0; mi < 4; ++mi) {
        int row = wm * 64 + mi * 16 + l16;
        int ch = (kc2 * 4 + quad) ^ (l16 & 7);
        a[mi] = *(const s16x8*)&ldsA[row * 64 + ch * 8];
      }
      #pragma unroll
      for (int ni = 0; ni < 4; ++ni) {
        int row = wn * 64 + ni * 16 + l16;
        int ch = (kc2 * 4 + quad) ^ (l16 & 7);
        b[ni] = *(const s16x8*)&ldsB[row * 64 + ch * 8];
      }
      #pragma unroll
      for (int mi = 0; mi < 4; ++mi)
        #pragma unroll
        for (int ni = 0; ni < 4; ++ni)
          acc[mi][ni] = __builtin_amdgcn_mfma_f32_16x16x32_bf16(a[mi], b[ni], acc[mi][ni], 0, 0, 0);
    }
  }
  for (int mi = 0; mi < 4; ++mi)
    for (int ni = 0; ni < 4; ++ni) {
      int row0 = wm * 64 + mi * 16 + quad * 4;
      int tg = nt * 128 + wn * 64 + ni * 16 + l16;
      if (tg >= ntok) continue;
      int bl = div784(tg);
      int n = tg - bl * N_;
      int oc0 = mt * 128 + row0;
      float4 bb = *(const float4*)&bp[oc0];
      float4 ss = *(const float4*)&sp[oc0];
      float4 tt = *(const float4*)&tp[oc0];
      float* o = out + ((size_t)(b0 + bl) * DIM_) * N_ + n;
      o[(size_t)(oc0 + 0) * N_] = (acc[mi][ni][0] + bb.x) * ss.x + tt.x;
      o[(size_t)(oc0 + 1) * N_] = (acc[mi][ni][1] + bb.y) * ss.y + tt.y;
      o[(size_t)(oc0 + 2) * N_] = (acc[mi][ni][2] + bb.z) * ss.z + tt.z;
      o[(size_t)(oc0 + 3) * N_] = (acc[mi][ni][3] + bb.w) * ss.w + tt.w;
    }
}

extern "C" void kernel_launch(void* const* d_in, const int* in_sizes, int n_in,
                              void* d_out, int out_size, void* d_ws, size_t ws_size,
                              hipStream_t stream) {
  (void)in_sizes; (void)n_in; (void)out_size;
  const float* x    = (const float*)d_in[0];
  const float* Wq   = (const float*)d_in[1];
  const float* bq   = (const float*)d_in[2];
  const float* sq   = (const float*)d_in[3];
  const float* tq   = (const float*)d_in[4];
  const float* Wk   = (const float*)d_in[5];
  const float* bk   = (const float*)d_in[6];
  const float* sk   = (const float*)d_in[7];
  const float* tk   = (const float*)d_in[8];
  const float* Wv   = (const float*)d_in[9];
  const float* bv   = (const float*)d_in[10];
  const float* sv   = (const float*)d_in[11];
  const float* tv   = (const float*)d_in[12];
  const float* Wvl  = (const float*)d_in[13];
  const float* bvl  = (const float*)d_in[14];
  const float* svl  = (const float*)d_in[15];
  const float* tvl  = (const float*)d_in[16];
  const float* th1w = (const float*)d_in[17];
  const float* th1b = (const float*)d_in[18];
  const float* th2w = (const float*)d_in[19];
  const float* th2b = (const float*)d_in[20];
  const float* ab   = (const float*)d_in[21];
  const float* Wp   = (const float*)d_in[22];
  const float* bp   = (const float*)d_in[23];
  const float* sp   = (const float*)d_in[24];
  const float* tp   = (const float*)d_in[25];
  float* out = (float*)d_out;

  char* ws = (char*)d_ws;
  size_t off = 0;
  auto alloc = [&](size_t bytes) -> void* {
    void* p = ws + off;
    off += (bytes + 255) & ~(size_t)255;
    return p;
  };

  u16* wqb = (u16*)alloc((size_t)256 * DIM_ * 2);
  u16* wkb = (u16*)alloc((size_t)256 * DIM_ * 2);
  u16* wvb = (u16*)alloc((size_t)DH_ * DIM_ * 2);
  u16* wpb = (u16*)alloc((size_t)DIM_ * DH_ * 2);
  float* abm = (float*)alloc((size_t)N_ * 8 * 4);
  size_t fixed = off;

  auto footprint = [fixed](int G) -> size_t {
    auto al = [](size_t b) { return (b + 255) & ~(size_t)255; };
    size_t a = fixed;
    a += al((size_t)G * H_ * N_ * KD_ * 2);   // qb
    a += al((size_t)G * H_ * N_ * KD_ * 2);   // kb
    a += al((size_t)G * DH_ * N_ * 2);        // vb
    a += al((size_t)G * DH_ * N_ * 2);        // vlb
    a += al((size_t)G * N_ * DH_ * 2);        // obb (xT aliases: DIM_ < DH_)
    a += al((size_t)8 * G * 8 * N_ * 4);      // Lbuf (up to 8 m-split partials)
    a += al((size_t)G * 8 * N_ * PSTR_ * 2);  // EP (e planes / P planes, full n)
    return a;
  };
  const int Gs[6] = {32, 16, 8, 4, 2, 1};
  int G = 1;
  for (int gi = 0; gi < 6; ++gi)
    if (footprint(Gs[gi]) <= ws_size) { G = Gs[gi]; break; }

  u16* qb  = (u16*)alloc((size_t)G * H_ * N_ * KD_ * 2);
  u16* kb  = (u16*)alloc((size_t)G * H_ * N_ * KD_ * 2);
  u16* vb  = (u16*)alloc((size_t)G * DH_ * N_ * 2);
  u16* vlb = (u16*)alloc((size_t)G * DH_ * N_ * 2);   // [bl][ch][n]
  u16* obb = (u16*)alloc((size_t)G * N_ * DH_ * 2);
  u16* xT  = obb;  // alias: xT dead after k_proj; obb written by k_pv strictly later
  float* Lbuf = (float*)alloc((size_t)8 * G * 8 * N_ * 4);
  u16* EP  = (u16*)alloc((size_t)G * 8 * N_ * PSTR_ * 2);

  CvtTab ct;
  ct.src[0] = Wq; ct.dst[0] = wqb; ct.n[0] = 256 * DIM_;
  ct.src[1] = Wk; ct.dst[1] = wkb; ct.n[1] = 256 * DIM_;
  ct.src[2] = Wv; ct.dst[2] = wvb; ct.n[2] = DH_ * DIM_;
  ct.src[3] = Wp; ct.dst[3] = wpb; ct.n[3] = DIM_ * DH_;
  hipLaunchKernelGGL(k_cvt, dim3(96, 4), dim3(256), 0, stream, ct);
  hipLaunchKernelGGL(k_abmix, dim3(25), dim3(256), 0, stream, ab, th1w, th1b, abm);

  int MO = (G >= 16) ? 4 : 8;
  int ntok = G * N_;
  int ttiles = (ntok + 127) / 128;
  for (int b0 = 0; b0 < B_; b0 += G) {
    hipLaunchKernelGGL(k_transpose, dim3(13, 6, G), dim3(256), 0, stream, x, xT, b0);
    hipLaunchKernelGGL(k_proj, dim3(ttiles, 12), dim3(256), 0, stream, xT,
                       wqb, wkb, wvb, bq, sq, tq, bk, sk, tk, bv, sv, tv, qb, kb, vb, ntok);
    hipLaunchKernelGGL(k_dwconv, dim3(DH_ / 4, G), dim3(256), 0, stream,
                       vb, Wvl, bvl, svl, tvl, vlb);
    hipLaunchKernelGGL(k_attn1, dim3(49, MO, G), dim3(256), 0, stream,
                       qb, kb, abm, th1w, Lbuf, EP);
    hipLaunchKernelGGL(k_attn2, dim3(N_, G), dim3(256), 0, stream,
                       Lbuf, th2w, th2b, EP, G, MO);
    hipLaunchKernelGGL(k_pv, dim3(7, 1, G * H_), dim3(256), 0, stream,
                       EP, vb, vlb, obb, 0, N_);
    hipLaunchKernelGGL(k_outproj, dim3(ttiles, 3), dim3(256), 0, stream,
                       obb, wpb, bp, sp, tp, out, b0, ntok);
  }
}

// Round 13
// 802.803 us; speedup vs baseline: 1.7372x; 1.0135x over previous
//
#include <hip/hip_runtime.h>
#include <hip/hip_bf16.h>

#define B_ 32
#define DIM_ 384
#define R_ 28
#define N_ 784
#define H_ 8
#define KD_ 32
#define D_ 128
#define DH_ 1024
#define PSTR_ 832
#define SCALE_ 0.17677669529663687f

typedef unsigned short u16;
typedef __attribute__((ext_vector_type(4))) float f32x4;
typedef __attribute__((ext_vector_type(8))) short s16x8;

__device__ __forceinline__ float b2f(u16 b) {
  union { unsigned int u; float f; } v; v.u = ((unsigned int)b) << 16; return v.f;
}
__device__ __forceinline__ u16 f2b(float f) {
  union { float f; unsigned int u; } v; v.f = f;
  unsigned int r = v.u + 0x7fffu + ((v.u >> 16) & 1u);
  return (u16)(r >> 16);
}
// y = m / 28 for m < 65536 (magic: 2341 = ceil(2^16/28))
__device__ __forceinline__ int div28(int m) { return (m * 2341) >> 16; }
// y = t / 784 for t < 25088 (magic: 5350 = ceil(2^22/784))
__device__ __forceinline__ int div784(int t) { return (int)(((long long)t * 5350) >> 22); }

// async global->LDS 16B copy. LDS dest is wave-uniform base + lane*16 (linear).
__device__ __forceinline__ void gl_lds16(const u16* g, u16* l) {
  __builtin_amdgcn_global_load_lds(
      (const __attribute__((address_space(1))) unsigned int*)g,
      (__attribute__((address_space(3))) unsigned int*)l, 16, 0, 0);
}

// ---------------- weight convert f32 -> bf16 (4 arrays) ----------------
struct CvtTab { const float* src[4]; u16* dst[4]; int n[4]; };

__global__ __launch_bounds__(256) void k_cvt(CvtTab tab) {
  int a = blockIdx.y;
  int n4 = tab.n[a] >> 2;
  const float4* s = (const float4*)tab.src[a];
  ushort4* d = (ushort4*)tab.dst[a];
  for (int i = blockIdx.x * 256 + threadIdx.x; i < n4; i += gridDim.x * 256) {
    float4 v = s[i];
    ushort4 o;
    o.x = f2b(v.x); o.y = f2b(v.y); o.z = f2b(v.z); o.w = f2b(v.w);
    d[i] = o;
  }
}

// ---------------- abmix: abm[idx][g] = sum_h th1w[g,h]*ab[h,idx] + th1b[g] ----------------
__global__ __launch_bounds__(256) void k_abmix(const float* __restrict__ ab,
                                               const float* __restrict__ th1w,
                                               const float* __restrict__ th1b,
                                               float* __restrict__ abm) {
  int t = blockIdx.x * 256 + threadIdx.x;
  if (t >= 8 * N_) return;
  int i = t >> 3, g = t & 7;
  float s = th1b[g];
  for (int h = 0; h < 8; ++h) s += th1w[g * 8 + h] * ab[h * N_ + i];
  abm[i * 8 + g] = s;
}

// ---------------- K0: transpose x(f32) [b][c][n] -> xT(bf16) [bl][n][c] ----------------
__global__ __launch_bounds__(256) void k_transpose(const float* __restrict__ x,
                                                   u16* __restrict__ xT, int b0) {
  __shared__ u16 tile[64][65];
  int nt = blockIdx.x, ct = blockIdx.y, bl = blockIdx.z;
  int t = threadIdx.x;
  int n0 = nt * 64, c0 = ct * 64;
  const float* xb = x + (size_t)(b0 + bl) * DIM_ * N_;
  int nl = t & 63, cg = t >> 6;
  for (int i = 0; i < 16; ++i) {
    int cl = cg * 16 + i;
    int n = n0 + nl;
    u16 val = 0;
    if (n < N_) val = f2b(xb[(size_t)(c0 + cl) * N_ + n]);
    tile[cl][nl] = val;
  }
  __syncthreads();
  u16* xTb = xT + (size_t)bl * N_ * DIM_;
  int cl = t & 63, ng = t >> 6;
  for (int i = 0; i < 16; ++i) {
    int n2 = n0 + ng * 16 + i;
    if (n2 < N_) xTb[(size_t)n2 * DIM_ + (c0 + cl)] = tile[cl][ng * 16 + i];
  }
}

// ---------------- K1: QKV projection, staged 128x128 tile, BK=64, XOR-swizzled LDS --------
__global__ __launch_bounds__(256) void k_proj(
    const u16* __restrict__ xT,
    const u16* __restrict__ wqb, const u16* __restrict__ wkb, const u16* __restrict__ wvb,
    const float* __restrict__ bq, const float* __restrict__ sq, const float* __restrict__ tq,
    const float* __restrict__ bk, const float* __restrict__ sk, const float* __restrict__ tk,
    const float* __restrict__ bv, const float* __restrict__ sv, const float* __restrict__ tv,
    u16* __restrict__ qb, u16* __restrict__ kb, u16* __restrict__ vb, int ntok) {
  __shared__ u16 ldsA[128 * 64];
  __shared__ u16 ldsB[128 * 64];
  int nt = blockIdx.x, mt = blockIdx.y;
  int t = threadIdx.x;
  int oc0 = mt * 128;
  const u16* Wsrc; const float *bsrc, *ssrc, *tsrc; int obase;
  if (mt < 2)      { Wsrc = wqb; bsrc = bq; ssrc = sq; tsrc = tq; obase = oc0; }
  else if (mt < 4) { Wsrc = wkb; bsrc = bk; ssrc = sk; tsrc = tk; obase = oc0 - 256; }
  else             { Wsrc = wvb; bsrc = bv; ssrc = sv; tsrc = tv; obase = oc0 - 512; }

  int lane = t & 63, wid = t >> 6;
  int wm = wid & 1, wn = wid >> 1;
  int l16 = lane & 15, quad = lane >> 4;

  f32x4 acc[4][4] = {};
  for (int kc = 0; kc < DIM_ / 64; ++kc) {
    __syncthreads();
    #pragma unroll
    for (int j = 0; j < 4; ++j) {
      int s = j * 256 + t;
      int row = s >> 3, ch = s & 7;
      int gc = (ch ^ (row & 7)) * 8;
      gl_lds16(Wsrc + (size_t)(obase + row) * DIM_ + kc * 64 + gc, ldsA + s * 8);
    }
    #pragma unroll
    for (int j = 0; j < 4; ++j) {
      int s = j * 256 + t;
      int row = s >> 3, ch = s & 7;
      int gc = (ch ^ (row & 7)) * 8;
      int tr = nt * 128 + row; if (tr >= ntok) tr = ntok - 1;
      gl_lds16(xT + (size_t)tr * DIM_ + kc * 64 + gc, ldsB + s * 8);
    }
    __syncthreads();
    #pragma unroll
    for (int kc2 = 0; kc2 < 2; ++kc2) {
      s16x8 a[4], b[4];
      #pragma unroll
      for (int mi = 0; mi < 4; ++mi) {
        int row = wm * 64 + mi * 16 + l16;
        int ch = (kc2 * 4 + quad) ^ (l16 & 7);
        a[mi] = *(const s16x8*)&ldsA[row * 64 + ch * 8];
      }
      #pragma unroll
      for (int ni = 0; ni < 4; ++ni) {
        int row = wn * 64 + ni * 16 + l16;
        int ch = (kc2 * 4 + quad) ^ (l16 & 7);
        b[ni] = *(const s16x8*)&ldsB[row * 64 + ch * 8];
      }
      #pragma unroll
      for (int mi = 0; mi < 4; ++mi)
        #pragma unroll
        for (int ni = 0; ni < 4; ++ni)
          acc[mi][ni] = __builtin_amdgcn_mfma_f32_16x16x32_bf16(a[mi], b[ni], acc[mi][ni], 0, 0, 0);
    }
  }
  for (int mi = 0; mi < 4; ++mi)
    for (int ni = 0; ni < 4; ++ni) {
      int row0 = wm * 64 + mi * 16 + quad * 4;
      int tg = nt * 128 + wn * 64 + ni * 16 + l16;
      if (tg >= ntok) continue;
      int bl = div784(tg);
      int col = tg - bl * N_;
      int ol0 = obase + row0;
      float4 bb = *(const float4*)&bsrc[ol0];
      float4 ss = *(const float4*)&ssrc[ol0];
      float4 tt = *(const float4*)&tsrc[ol0];
      float v0 = (acc[mi][ni][0] + bb.x) * ss.x + tt.x;
      float v1 = (acc[mi][ni][1] + bb.y) * ss.y + tt.y;
      float v2 = (acc[mi][ni][2] + bb.z) * ss.z + tt.z;
      float v3 = (acc[mi][ni][3] + bb.w) * ss.w + tt.w;
      int oc = oc0 + row0;
      if (oc < 512) {
        int h = (oc & 255) >> 5, c0 = oc & 31;
        u16* dst = (oc < 256) ? qb : kb;
        ushort4 o;
        o.x = f2b(v0); o.y = f2b(v1); o.z = f2b(v2); o.w = f2b(v3);
        *(ushort4*)&dst[(((size_t)bl * H_ + h) * N_ + col) * KD_ + c0] = o;
      } else {
        int ch = oc - 512;
        vb[((size_t)bl * DH_ + ch) * N_ + col] = f2b(v0);
        vb[((size_t)bl * DH_ + ch + 1) * N_ + col] = f2b(v1);
        vb[((size_t)bl * DH_ + ch + 2) * N_ + col] = f2b(v2);
        vb[((size_t)bl * DH_ + ch + 3) * N_ + col] = f2b(v3);
      }
    }
}

// ---------------- K2: depthwise 3x3 conv + affine; wave-per-channel ----------------
__global__ __launch_bounds__(256) void k_dwconv(
    const u16* __restrict__ vb, const float* __restrict__ Wvl,
    const float* __restrict__ bvl, const float* __restrict__ svl, const float* __restrict__ tvl,
    u16* __restrict__ vlb) {
  __shared__ u16 img[4][N_];
  int cg = blockIdx.x, bl = blockIdx.y;
  int t = threadIdx.x;
  int wid = t >> 6, lane = t & 63;
  int ch = cg * 4 + wid;
  const u16* vp = vb + ((size_t)bl * DH_ + ch) * N_;
  for (int i = lane; i < N_; i += 64) img[wid][i] = vp[i];
  __syncthreads();
  float w[9];
  for (int i = 0; i < 9; ++i) w[i] = Wvl[ch * 9 + i];
  float bias = bvl[ch], sc = svl[ch], sh = tvl[ch];
  u16* op = vlb + ((size_t)bl * DH_ + ch) * N_;
  for (int p = lane; p < N_; p += 64) {
    int y = p / R_, x = p - y * R_;
    float acc = 0.f;
    #pragma unroll
    for (int dy = -1; dy <= 1; ++dy) {
      int yy = y + dy;
      if (yy < 0 || yy >= R_) continue;
      #pragma unroll
      for (int dx = -1; dx <= 1; ++dx) {
        int xx = x + dx;
        if (xx < 0 || xx >= R_) continue;
        acc += b2f(img[wid][yy * R_ + xx]) * w[(dy + 1) * 3 + (dx + 1)];
      }
    }
    op[p] = f2b((acc + bias) * sc + sh);
  }
}

// ---------------- K3a: attention pass 1 -------------------------------------------------
// Grid (49 ntile, MO msplit, G). Computes e = exp(mix1(QK^T)+abmix) for its m-slice,
// accumulates partial L into Lbuf[mo][bl][g][n] AND stores e (bf16) into EP g-planes.
// Scalar fmaf mix1 (84-120 VGPR proven; r9 ERRATA: f32x4 vector exprs -> 216 VGPR, 2.3x slower).
__global__ __launch_bounds__(256) void k_attn1(
    const u16* __restrict__ qb, const u16* __restrict__ kb,
    const float* __restrict__ abm, const float* __restrict__ th1w,
    float* __restrict__ Lbuf, u16* __restrict__ EP) {
  __shared__ float abms[N_ * 8];
  __shared__ float w1Ts[64];
  __shared__ float lred[4][8][16];
  int nt = blockIdx.x, mo = blockIdx.y, bl = blockIdx.z;
  int MO = gridDim.y;
  int G = gridDim.z;
  int t = threadIdx.x;
  for (int i = t; i < N_ * 8; i += 256) abms[i] = abm[i];
  if (t < 64) w1Ts[(t & 7) * 8 + (t >> 3)] = th1w[t];
  __syncthreads();

  int lane = t & 63, wid = t >> 6;
  int l16 = lane & 15, quad = lane >> 4;
  int koff = quad * 8;
  int n_g = nt * 16 + l16;             // < 784 always (49*16=784)
  int yn = div28(n_g), xn = n_g - yn * R_;
  size_t blb = (size_t)bl * H_ * N_;

  s16x8 qf[8];
  #pragma unroll
  for (int h = 0; h < 8; ++h)
    qf[h] = *(const s16x8*)&qb[(blb + (size_t)h * N_ + n_g) * KD_ + koff];

  float Lp[8] = {};
  #pragma unroll 1
  for (int s = mo; s < 13; s += MO) {
    int mb = s * 64 + wid * 16;
    if (mb >= N_) continue;           // wave-uniform
    f32x4 sm8[8] = {};
    #pragma unroll
    for (int h = 0; h < 8; ++h) {
      s16x8 af = *(const s16x8*)&kb[(blb + (size_t)h * N_ + mb + l16) * KD_ + koff];
      f32x4 acc = {};
      acc = __builtin_amdgcn_mfma_f32_16x16x32_bf16(af, qf[h], acc, 0, 0, 0);
      f32x4 wA = *(const f32x4*)&w1Ts[h * 8];
      f32x4 wB = *(const f32x4*)&w1Ts[h * 8 + 4];
      #pragma unroll
      for (int g = 0; g < 4; ++g)
        #pragma unroll
        for (int r = 0; r < 4; ++r) {
          sm8[g][r] = fmaf(wA[g], acc[r], sm8[g][r]);
          sm8[g + 4][r] = fmaf(wB[g], acc[r], sm8[g + 4][r]);
        }
    }
    int mc = mb + quad * 4;
    int idx4[4];
    #pragma unroll
    for (int r = 0; r < 4; ++r) {
      int m = mc + r;
      int ym = div28(m), xm = m - ym * R_;
      int dy = yn - ym; dy = dy < 0 ? -dy : dy;
      int dx = xn - xm; dx = dx < 0 ? -dx : dx;
      idx4[r] = (dy * R_ + dx) * 8;
    }
    #pragma unroll
    for (int g = 0; g < 8; ++g) {
      float e0 = __expf(fmaf(sm8[g][0], SCALE_, abms[idx4[0] + g]));
      float e1 = __expf(fmaf(sm8[g][1], SCALE_, abms[idx4[1] + g]));
      float e2 = __expf(fmaf(sm8[g][2], SCALE_, abms[idx4[2] + g]));
      float e3 = __expf(fmaf(sm8[g][3], SCALE_, abms[idx4[3] + g]));
      Lp[g] += (e0 + e1) + (e2 + e3);
      ushort4 ov;
      ov.x = f2b(e0); ov.y = f2b(e1); ov.z = f2b(e2); ov.w = f2b(e3);
      *(ushort4*)&EP[((size_t)(bl * 8 + g) * N_ + n_g) * PSTR_ + mc] = ov;
    }
  }
  #pragma unroll
  for (int g = 0; g < 8; ++g) {
    Lp[g] += __shfl_xor(Lp[g], 16);
    Lp[g] += __shfl_xor(Lp[g], 32);
  }
  if (quad == 0)
    #pragma unroll
    for (int g = 0; g < 8; ++g) lred[wid][g][l16] = Lp[g];
  __syncthreads();
  if (t < 128) {
    int g = t >> 4, nn = t & 15;
    float L = lred[0][g][nn] + lred[1][g][nn] + lred[2][g][nn] + lred[3][g][nn];
    Lbuf[(((size_t)mo * G + bl) * 8 + g) * N_ + nt * 16 + nn] = L;
  }
}

// ---------------- K3b: in-place normalize + th2-mix: EP g-planes -> P f-planes ----------
// Grid (392 n-pairs, G). Block handles two (bl,n) rows; r12: 2 rows/block doubles
// per-thread MLP (16 loads in flight; row-1 loads hide under row-0 mix compute).
// Reads e[8g] at its mc, writes P[8f] at same addresses (read-before-write per thread;
// threads touch disjoint mc -> race-free). Pad m in [784,832) written zero for k_pv.
__global__ __launch_bounds__(256) void k_attn2(
    const float* __restrict__ Lbuf, const float* __restrict__ th2w,
    const float* __restrict__ th2b, u16* __restrict__ EP, int G, int MO) {
  __shared__ float w2s[64], b2s[8], linv[2][8];
  int n0 = blockIdx.x * 2, bl = blockIdx.y;
  int t = threadIdx.x;
  if (t < 64) w2s[t] = th2w[t];
  if (t < 8) b2s[t] = th2b[t];
  if (t < 16) {
    int rr = t >> 3, g = t & 7;
    float L = 0.f;
    for (int p = 0; p < MO; ++p)
      L += Lbuf[(((size_t)p * G + bl) * 8 + g) * N_ + (n0 + rr)];
    linv[rr][g] = 1.f / L;
  }
  __syncthreads();
  if (t >= PSTR_ / 4) return;
  int mc = t * 4;
  const size_t pstr = (size_t)N_ * PSTR_;
  size_t base0 = ((size_t)bl * 8 * N_ + n0) * (size_t)PSTR_ + mc;
  size_t base1 = base0 + PSTR_;
  if (mc >= N_) {
    ushort4 z = {0, 0, 0, 0};
    #pragma unroll
    for (int f = 0; f < 8; ++f) {
      *(ushort4*)&EP[base0 + (size_t)f * pstr] = z;
      *(ushort4*)&EP[base1 + (size_t)f * pstr] = z;
    }
    return;
  }
  // issue all 16 plane loads (both rows) for max memory-level parallelism
  ushort4 raw0[8], raw1[8];
  #pragma unroll
  for (int g = 0; g < 8; ++g) {
    raw0[g] = *(const ushort4*)&EP[base0 + (size_t)g * pstr];
    raw1[g] = *(const ushort4*)&EP[base1 + (size_t)g * pstr];
  }
  float e0[8][4], e1[8][4];
  #pragma unroll
  for (int g = 0; g < 8; ++g) {
    float la = linv[0][g], lb = linv[1][g];
    e0[g][0] = b2f(raw0[g].x) * la; e0[g][1] = b2f(raw0[g].y) * la;
    e0[g][2] = b2f(raw0[g].z) * la; e0[g][3] = b2f(raw0[g].w) * la;
    e1[g][0] = b2f(raw1[g].x) * lb; e1[g][1] = b2f(raw1[g].y) * lb;
    e1[g][2] = b2f(raw1[g].z) * lb; e1[g][3] = b2f(raw1[g].w) * lb;
  }
  // streaming mix2 per row; unroll 1 is load-bearing for VGPR budget (r7 lesson)
  #pragma unroll 1
  for (int f = 0; f < 8; ++f) {
    float b = b2s[f];
    float o0 = b, o1 = b, o2 = b, o3 = b;
    #pragma unroll
    for (int g = 0; g < 8; ++g) {
      float w = w2s[f * 8 + g];
      o0 = fmaf(w, e0[g][0], o0); o1 = fmaf(w, e0[g][1], o1);
      o2 = fmaf(w, e0[g][2], o2); o3 = fmaf(w, e0[g][3], o3);
    }
    ushort4 ov;
    ov.x = f2b(o0); ov.y = f2b(o1); ov.z = f2b(o2); ov.w = f2b(o3);
    *(ushort4*)&EP[base0 + (size_t)f * pstr] = ov;
  }
  #pragma unroll 1
  for (int f = 0; f < 8; ++f) {
    float b = b2s[f];
    float o0 = b, o1 = b, o2 = b, o3 = b;
    #pragma unroll
    for (int g = 0; g < 8; ++g) {
      float w = w2s[f * 8 + g];
      o0 = fmaf(w, e1[g][0], o0); o1 = fmaf(w, e1[g][1], o1);
      o2 = fmaf(w, e1[g][2], o2); o3 = fmaf(w, e1[g][3], o3);
    }
    ushort4 ov;
    ov.x = f2b(o0); ov.y = f2b(o1); ov.z = f2b(o2); ov.w = f2b(o3);
    *(ushort4*)&EP[base1 + (size_t)f * pstr] = ov;
  }
}

// ---------------- K5: O' = relu(attn @ V + vl), staged, K=832 (P zero-padded) -------------
// A = V (rows d=128), B = P (rows n, stride PSTR_). acc row=d, col=n.
__global__ __launch_bounds__(256) void k_pv(
    const u16* __restrict__ P, const u16* __restrict__ vb, const u16* __restrict__ vlb,
    u16* __restrict__ ob, int n0, int NC) {
  __shared__ u16 ldsA[128 * 64];
  __shared__ u16 ldsB[128 * 64];
  int ntl = blockIdx.x, z = blockIdx.z;
  int bl = z >> 3, f = z & 7;
  int t = threadIdx.x;
  int lane = t & 63, wid = t >> 6;
  int wm = wid & 1, wn = wid >> 1;
  int l16 = lane & 15, quad = lane >> 4;

  const u16* vsrc = vb + ((size_t)bl * DH_ + f * D_) * N_;
  const u16* asrc = P + ((size_t)bl * H_ + f) * (size_t)NC * PSTR_;

  f32x4 acc[4][4] = {};
  for (int kc = 0; kc < PSTR_ / 64; ++kc) {
    __syncthreads();
    #pragma unroll
    for (int j = 0; j < 4; ++j) {
      int s = j * 256 + t;
      int row = s >> 3, ch = s & 7;
      int gc = (ch ^ (row & 7)) * 8;
      gl_lds16(vsrc + (size_t)row * N_ + kc * 64 + gc, ldsA + s * 8);
    }
    #pragma unroll
    for (int j = 0; j < 4; ++j) {
      int s = j * 256 + t;
      int row = s >> 3, ch = s & 7;
      int gc = (ch ^ (row & 7)) * 8;
      int nr = ntl * 128 + row; if (nr >= NC) nr = NC - 1;
      gl_lds16(asrc + (size_t)nr * PSTR_ + kc * 64 + gc, ldsB + s * 8);
    }
    __syncthreads();
    #pragma unroll
    for (int kc2 = 0; kc2 < 2; ++kc2) {
      s16x8 a[4], b[4];
      #pragma unroll
      for (int mi = 0; mi < 4; ++mi) {
        int row = wm * 64 + mi * 16 + l16;
        int ch = (kc2 * 4 + quad) ^ (l16 & 7);
        a[mi] = *(const s16x8*)&ldsA[row * 64 + ch * 8];
      }
      #pragma unroll
      for (int ni = 0; ni < 4; ++ni) {
        int row = wn * 64 + ni * 16 + l16;
        int ch = (kc2 * 4 + quad) ^ (l16 & 7);
        b[ni] = *(const s16x8*)&ldsB[row * 64 + ch * 8];
      }
      #pragma unroll
      for (int mi = 0; mi < 4; ++mi)
        #pragma unroll
        for (int ni = 0; ni < 4; ++ni)
          acc[mi][ni] = __builtin_amdgcn_mfma_f32_16x16x32_bf16(a[mi], b[ni], acc[mi][ni], 0, 0, 0);
    }
  }
  for (int mi = 0; mi < 4; ++mi)
    for (int ni = 0; ni < 4; ++ni) {
      int row = wm * 64 + mi * 16 + quad * 4;
      int col = wn * 64 + ni * 16 + l16;
      int nloc = ntl * 128 + col;
      if (nloc >= NC || (n0 + nloc) >= N_) continue;
      int ch = f * D_ + row;
      size_t vaddr = ((size_t)bl * DH_ + ch) * N_ + (n0 + nloc);
      float o0 = acc[mi][ni][0] + b2f(vlb[vaddr]);
      float o1 = acc[mi][ni][1] + b2f(vlb[vaddr + N_]);
      float o2 = acc[mi][ni][2] + b2f(vlb[vaddr + 2 * N_]);
      float o3 = acc[mi][ni][3] + b2f(vlb[vaddr + 3 * N_]);
      size_t addr = ((size_t)bl * N_ + (n0 + nloc)) * DH_ + ch;
      ushort4 o4;
      o4.x = f2b(o0 > 0.f ? o0 : 0.f);
      o4.y = f2b(o1 > 0.f ? o1 : 0.f);
      o4.z = f2b(o2 > 0.f ? o2 : 0.f);
      o4.w = f2b(o3 > 0.f ? o3 : 0.f);
      *(ushort4*)&ob[addr] = o4;
    }
}

// ---------------- K6: out = affine(Wp @ O' + bp), staged, f32 out ----------------
__global__ __launch_bounds__(256) void k_outproj(
    const u16* __restrict__ ob, const u16* __restrict__ wpb,
    const float* __restrict__ bp, const float* __restrict__ sp, const float* __restrict__ tp,
    float* __restrict__ out, int b0, int ntok) {
  __shared__ u16 ldsA[128 * 64];
  __shared__ u16 ldsB[128 * 64];
  int nt = blockIdx.x, mt = blockIdx.y;
  int t = threadIdx.x;
  int lane = t & 63, wid = t >> 6;
  int wm = wid & 1, wn = wid >> 1;
  int l16 = lane & 15, quad = lane >> 4;

  f32x4 acc[4][4] = {};
  for (int kc = 0; kc < DH_ / 64; ++kc) {
    __syncthreads();
    #pragma unroll
    for (int j = 0; j < 4; ++j) {
      int s = j * 256 + t;
      int row = s >> 3, ch = s & 7;
      int gc = (ch ^ (row & 7)) * 8;
      gl_lds16(wpb + (size_t)(mt * 128 + row) * DH_ + kc * 64 + gc, ldsA + s * 8);
    }
    #pragma unroll
    for (int j = 0; j < 4; ++j) {
      int s = j * 256 + t;
      int row = s >> 3, ch = s & 7;
      int gc = (ch ^ (row & 7)) * 8;
      int tr = nt * 128 + row; if (tr >= ntok) tr = ntok - 1;
      gl_lds16(ob + (size_t)tr * DH_ + kc * 64 + gc, ldsB + s * 8);
    }
    __syncthreads();
    #pragma unroll
    for (int kc2 = 0; kc2 < 2; ++kc2) {
      s16x8 a[4], b[4];
      #pragma unroll
      for (int mi = 0; mi < 4; ++mi) {
        int row = wm * 64 + mi * 16 + l16;
        int ch = (kc2 * 4 + quad) ^ (l16 & 7);
        a[mi] = *(const s16x8*)&ldsA[row * 64 + ch * 8];
      }
      #pragma unroll
      for (int ni = 0; ni < 4; ++ni) {
        int row = wn * 64 + ni * 16 + l16;
        int ch = (kc2 * 4 + quad) ^ (l16 & 7);
        b[ni] = *(const s16x8*)&ldsB[row * 64 + ch * 8];
      }
      #pragma unroll
      for (int mi = 0; mi < 4; ++mi)
        #pragma unroll
        for (int ni = 0; ni < 4; ++ni)
          acc[mi][ni] = __builtin_amdgcn_mfma_f32_16x16x32_bf16(a[mi], b[ni], acc[mi][ni], 0, 0, 0);
    }
  }
  for (int mi = 0; mi < 4; ++mi)
    for (int ni = 0; ni < 4; ++ni) {
      int row0 = wm * 64 + mi * 16 + quad * 4;
      int tg = nt * 128 + wn * 64 + ni * 16 + l16;
      if (tg >= ntok) continue;
      int bl = div784(tg);
      int n = tg - bl * N_;
      int oc0 = mt * 128 + row0;
      float4 bb = *(const float4*)&bp[oc0];
      float4 ss = *(const float4*)&sp[oc0];
      float4 tt = *(const float4*)&tp[oc0];
      float* o = out + ((size_t)(b0 + bl) * DIM_) * N_ + n;
      o[(size_t)(oc0 + 0) * N_] = (acc[mi][ni][0] + bb.x) * ss.x + tt.x;
      o[(size_t)(oc0 + 1) * N_] = (acc[mi][ni][1] + bb.y) * ss.y + tt.y;
      o[(size_t)(oc0 + 2) * N_] = (acc[mi][ni][2] + bb.z) * ss.z + tt.z;
      o[(size_t)(oc0 + 3) * N_] = (acc[mi][ni][3] + bb.w) * ss.w + tt.w;
    }
}

extern "C" void kernel_launch(void* const* d_in, const int* in_sizes, int n_in,
                              void* d_out, int out_size, void* d_ws, size_t ws_size,
                              hipStream_t stream) {
  (void)in_sizes; (void)n_in; (void)out_size;
  const float* x    = (const float*)d_in[0];
  const float* Wq   = (const float*)d_in[1];
  const float* bq   = (const float*)d_in[2];
  const float* sq   = (const float*)d_in[3];
  const float* tq   = (const float*)d_in[4];
  const float* Wk   = (const float*)d_in[5];
  const float* bk   = (const float*)d_in[6];
  const float* sk   = (const float*)d_in[7];
  const float* tk   = (const float*)d_in[8];
  const float* Wv   = (const float*)d_in[9];
  const float* bv   = (const float*)d_in[10];
  const float* sv   = (const float*)d_in[11];
  const float* tv   = (const float*)d_in[12];
  const float* Wvl  = (const float*)d_in[13];
  const float* bvl  = (const float*)d_in[14];
  const float* svl  = (const float*)d_in[15];
  const float* tvl  = (const float*)d_in[16];
  const float* th1w = (const float*)d_in[17];
  const float* th1b = (const float*)d_in[18];
  const float* th2w = (const float*)d_in[19];
  const float* th2b = (const float*)d_in[20];
  const float* ab   = (const float*)d_in[21];
  const float* Wp   = (const float*)d_in[22];
  const float* bp   = (const float*)d_in[23];
  const float* sp   = (const float*)d_in[24];
  const float* tp   = (const float*)d_in[25];
  float* out = (float*)d_out;

  char* ws = (char*)d_ws;
  size_t off = 0;
  auto alloc = [&](size_t bytes) -> void* {
    void* p = ws + off;
    off += (bytes + 255) & ~(size_t)255;
    return p;
  };

  u16* wqb = (u16*)alloc((size_t)256 * DIM_ * 2);
  u16* wkb = (u16*)alloc((size_t)256 * DIM_ * 2);
  u16* wvb = (u16*)alloc((size_t)DH_ * DIM_ * 2);
  u16* wpb = (u16*)alloc((size_t)DIM_ * DH_ * 2);
  float* abm = (float*)alloc((size_t)N_ * 8 * 4);
  size_t fixed = off;

  auto footprint = [fixed](int G) -> size_t {
    auto al = [](size_t b) { return (b + 255) & ~(size_t)255; };
    size_t a = fixed;
    a += al((size_t)G * H_ * N_ * KD_ * 2);   // qb
    a += al((size_t)G * H_ * N_ * KD_ * 2);   // kb
    a += al((size_t)G * DH_ * N_ * 2);        // vb
    a += al((size_t)G * DH_ * N_ * 2);        // vlb
    a += al((size_t)G * N_ * DH_ * 2);        // obb (xT aliases: DIM_ < DH_)
    a += al((size_t)8 * G * 8 * N_ * 4);      // Lbuf (up to 8 m-split partials)
    a += al((size_t)G * 8 * N_ * PSTR_ * 2);  // EP (e planes / P planes, full n)
    return a;
  };
  const int Gs[6] = {32, 16, 8, 4, 2, 1};
  int G = 1;
  for (int gi = 0; gi < 6; ++gi)
    if (footprint(Gs[gi]) <= ws_size) { G = Gs[gi]; break; }

  u16* qb  = (u16*)alloc((size_t)G * H_ * N_ * KD_ * 2);
  u16* kb  = (u16*)alloc((size_t)G * H_ * N_ * KD_ * 2);
  u16* vb  = (u16*)alloc((size_t)G * DH_ * N_ * 2);
  u16* vlb = (u16*)alloc((size_t)G * DH_ * N_ * 2);   // [bl][ch][n]
  u16* obb = (u16*)alloc((size_t)G * N_ * DH_ * 2);
  u16* xT  = obb;  // alias: xT dead after k_proj; obb written by k_pv strictly later
  float* Lbuf = (float*)alloc((size_t)8 * G * 8 * N_ * 4);
  u16* EP  = (u16*)alloc((size_t)G * 8 * N_ * PSTR_ * 2);

  CvtTab ct;
  ct.src[0] = Wq; ct.dst[0] = wqb; ct.n[0] = 256 * DIM_;
  ct.src[1] = Wk; ct.dst[1] = wkb; ct.n[1] = 256 * DIM_;
  ct.src[2] = Wv; ct.dst[2] = wvb; ct.n[2] = DH_ * DIM_;
  ct.src[3] = Wp; ct.dst[3] = wpb; ct.n[3] = DIM_ * DH_;
  hipLaunchKernelGGL(k_cvt, dim3(96, 4), dim3(256), 0, stream, ct);
  hipLaunchKernelGGL(k_abmix, dim3(25), dim3(256), 0, stream, ab, th1w, th1b, abm);

  int MO = (G >= 16) ? 4 : 8;
  int ntok = G * N_;
  int ttiles = (ntok + 127) / 128;
  for (int b0 = 0; b0 < B_; b0 += G) {
    hipLaunchKernelGGL(k_transpose, dim3(13, 6, G), dim3(256), 0, stream, x, xT, b0);
    hipLaunchKernelGGL(k_proj, dim3(ttiles, 12), dim3(256), 0, stream, xT,
                       wqb, wkb, wvb, bq, sq, tq, bk, sk, tk, bv, sv, tv, qb, kb, vb, ntok);
    hipLaunchKernelGGL(k_dwconv, dim3(DH_ / 4, G), dim3(256), 0, stream,
                       vb, Wvl, bvl, svl, tvl, vlb);
    hipLaunchKernelGGL(k_attn1, dim3(49, MO, G), dim3(256), 0, stream,
                       qb, kb, abm, th1w, Lbuf, EP);
    hipLaunchKernelGGL(k_attn2, dim3(N_ / 2, G), dim3(256), 0, stream,
                       Lbuf, th2w, th2b, EP, G, MO);
    hipLaunchKernelGGL(k_pv, dim3(7, 1, G * H_), dim3(256), 0, stream,
                       EP, vb, vlb, obb, 0, N_);
    hipLaunchKernelGGL(k_outproj, dim3(ttiles, 3), dim3(256), 0, stream,
                       obb, wpb, bp, sp, tp, out, b0, ntok);
  }
}